// Round 6
// baseline (430.418 us; speedup 1.0000x reference)
//
#include <hip/hip_runtime.h>
#include <hip/hip_fp16.h>

#define N_NODES 50000
#define MPAD    50048            // 391 * 128
#define N_EDGES 500000
#define F_IN    112
#define K1P     128              // F_IN padded to 32-multiple
#define F1      336
#define K2P     352              // F1 padded to 32-multiple
#define F2      168
#define NGRAPH  256
#define SCAN_CHUNK 1024
#define SCAN_BLOCKS ((N_NODES + SCAN_CHUNK - 1) / SCAN_CHUNK)   // 49

typedef __attribute__((ext_vector_type(8))) __bf16 bf16x8;
typedef __attribute__((ext_vector_type(4))) float f32x4;
typedef unsigned short ushort_t;

__device__ __forceinline__ ushort_t bf16_rne(float x) {
    unsigned u = __float_as_uint(x);
    unsigned r = u + 0x7FFF + ((u >> 16) & 1);
    return (ushort_t)(r >> 16);
}
__device__ __forceinline__ float bf16_tof(ushort_t h) {
    return __uint_as_float(((unsigned)h) << 16);
}

// ---------------- small utility kernels ----------------
__global__ void k_zero_int(int* p, int n) {
    int i = blockIdx.x * blockDim.x + threadIdx.x;
    if (i < n) p[i] = 0;
}
__global__ void k_count_deg(const int* __restrict__ dst, int* __restrict__ dcount, int e) {
    int i = blockIdx.x * blockDim.x + threadIdx.x;
    if (i < e) atomicAdd(&dcount[dst[i]], 1);
}
__global__ void k_dinv(const int* __restrict__ dcount, float* __restrict__ dinv, int n) {
    int i = blockIdx.x * blockDim.x + threadIdx.x;
    if (i < n) dinv[i] = rsqrtf((float)dcount[i] + 1.0f);   // +1 self-loop
}
__global__ void k_ranges(const int* __restrict__ batch, int* __restrict__ r0,
                         int* __restrict__ r1, int n) {
    int v = blockIdx.x * blockDim.x + threadIdx.x;
    if (v >= n) return;
    int b = batch[v];
    if (v == 0 || batch[v - 1] != b) r0[b] = v;
    if (v == n - 1 || batch[v + 1] != b) r1[b] = v + 1;
}
// X fp32 -> fp16 (4 elems/thread)
__global__ void k_cvtX(const float* __restrict__ X, ushort_t* __restrict__ X16, int total4) {
    int i = blockIdx.x * blockDim.x + threadIdx.x;
    if (i >= total4) return;
    float4 v = ((const float4*)X)[i];
    __half2 h0 = __floats2half2_rn(v.x, v.y);
    __half2 h1 = __floats2half2_rn(v.z, v.w);
    uint2 u;
    u.x = *(unsigned*)&h0;
    u.y = *(unsigned*)&h1;
    ((uint2*)X16)[i] = u;
}

// ---------------- exclusive scan of dcount -> off ----------------
__global__ __launch_bounds__(SCAN_CHUNK) void k_scan1(const int* __restrict__ dcount,
                                                      int* __restrict__ off,
                                                      int* __restrict__ partials, int n) {
    __shared__ int s[SCAN_CHUNK];
    int t = threadIdx.x;
    int i = blockIdx.x * SCAN_CHUNK + t;
    int val = (i < n) ? dcount[i] : 0;
    s[t] = val;
    __syncthreads();
    for (int d = 1; d < SCAN_CHUNK; d <<= 1) {
        int x = (t >= d) ? s[t - d] : 0;
        __syncthreads();
        s[t] += x;
        __syncthreads();
    }
    if (i < n) off[i] = s[t] - val;
    if (t == SCAN_CHUNK - 1) partials[blockIdx.x] = s[t];
}
__global__ void k_scan2(int* __restrict__ partials, int* __restrict__ off, int nblk, int n) {
    if (threadIdx.x == 0 && blockIdx.x == 0) {
        int run = 0;
        for (int j = 0; j < nblk; ++j) { int p = partials[j]; partials[j] = run; run += p; }
        off[n] = run;
    }
}
__global__ __launch_bounds__(SCAN_CHUNK) void k_scan3(int* __restrict__ off,
                                                      const int* __restrict__ partials, int n) {
    int i = blockIdx.x * SCAN_CHUNK + threadIdx.x;
    if (i < n) off[i] += partials[blockIdx.x];
}

// ---------------- scatter edges into dst-sorted CSR, packed (src, coef) ----------------
__global__ void k_scatter(const int* __restrict__ src, const int* __restrict__ dst,
                          const int* __restrict__ off, int* __restrict__ cur,
                          const float* __restrict__ dinv,
                          int2* __restrict__ csr, int e) {
    int i = blockIdx.x * blockDim.x + threadIdx.x;
    if (i >= e) return;
    int s = src[i], d = dst[i];
    int pos = atomicAdd(&cur[d], 1);
    int2 rec;
    rec.x = s;
    rec.y = __float_as_int(dinv[s] * dinv[d]);
    csr[off[d] + pos] = rec;
}

// ---------------- weight transpose + bf16 split: W[K,N] -> Wh/Wl[NP][KP] ----------------
template<int K, int N, int KP, int NP>
__global__ void k_cvtW(const float* __restrict__ W, ushort_t* __restrict__ Wh,
                       ushort_t* __restrict__ Wl) {
    int idx = blockIdx.x * 256 + threadIdx.x;
    if (idx >= NP * KP) return;
    int n = idx / KP, k = idx % KP;
    float v = (n < N && k < K) ? W[k * N + n] : 0.0f;
    ushort_t h = bf16_rne(v);
    ushort_t l = bf16_rne(v - bf16_tof(h));
    Wh[idx] = h;
    Wl[idx] = l;
}

// ---------------- agg layer 1: A_norm @ X16 -> bf16 hi/lo planes [MPAD][K1P] ----------------
__global__ __launch_bounds__(256) void k_agg1(const ushort_t* __restrict__ X16,
                                              const int* __restrict__ off,
                                              const int2* __restrict__ csr,
                                              const float* __restrict__ dinv,
                                              ushort_t* __restrict__ aXh,
                                              ushort_t* __restrict__ aXl) {
    int gw = (blockIdx.x * 256 + threadIdx.x) >> 6;
    int lane = threadIdx.x & 63;
    if (gw >= N_NODES) return;
    const int v = gw;
    const int NV = F_IN / 2;      // 56 active lanes, each 2 fp16
    int o0 = off[v], o1 = off[v + 1];
    int n = o1 - o0;
    float di = dinv[v];
    float2 acc = {0.0f, 0.0f};
    if (lane < NV) {
        __half2 hv = ((const __half2*)(X16 + (long)v * F_IN))[lane];
        float2 xv = __half22float2(hv);
        float s2 = di * di;
        acc.x = xv.x * s2; acc.y = xv.y * s2;
    }
    int2 e0, e1; float2 t0 = {0, 0}, t1 = {0, 0};
    if (n > 0) {
        e0 = csr[o0];
        if (lane < NV) t0 = __half22float2(((const __half2*)(X16 + (long)e0.x * F_IN))[lane]);
    }
    if (n > 1) {
        e1 = csr[o0 + 1];
        if (lane < NV) t1 = __half22float2(((const __half2*)(X16 + (long)e1.x * F_IN))[lane]);
    }
    for (int i = o0 + 2; i < o1; ++i) {
        int2 e2 = csr[i];
        float2 t2 = {0, 0};
        if (lane < NV) t2 = __half22float2(((const __half2*)(X16 + (long)e2.x * F_IN))[lane]);
        float c = __int_as_float(e0.y);
        acc.x += c * t0.x; acc.y += c * t0.y;
        e0 = e1; t0 = t1; e1 = e2; t1 = t2;
    }
    if (n > 1) { float c = __int_as_float(e0.y); acc.x += c * t0.x; acc.y += c * t0.y; e0 = e1; t0 = t1; }
    if (n > 0) { float c = __int_as_float(e0.y); acc.x += c * t0.x; acc.y += c * t0.y; }
    unsigned vh = 0, vl = 0;
    if (lane < NV) {
        ushort_t h0 = bf16_rne(acc.x); ushort_t l0 = bf16_rne(acc.x - bf16_tof(h0));
        ushort_t h1 = bf16_rne(acc.y); ushort_t l1 = bf16_rne(acc.y - bf16_tof(h1));
        vh = (unsigned)h0 | ((unsigned)h1 << 16);
        vl = (unsigned)l0 | ((unsigned)l1 << 16);
    }
    ((unsigned*)(aXh + (long)v * K1P))[lane] = vh;
    ((unsigned*)(aXl + (long)v * K1P))[lane] = vl;
}

// ---------------- MFMA split-bf16 GEMM: C = A[M,KP] @ Bt[N,KP]^T ----------------
// 128x64 block tile, 4 waves (2x2), each wave 64x32 via 16x16x32 MFMA.
// EPI==1: C -> bf16 hi/lo planes width CW (relu(acc+bias) for col<Nreal, 0 pad beyond)
// EPI==2: C -> fp16 plane width Nreal
template<int KP, int EPI>
__global__ __launch_bounds__(256) void k_gemm_mfma(
        const ushort_t* __restrict__ Ah, const ushort_t* __restrict__ Al,
        const ushort_t* __restrict__ Bh, const ushort_t* __restrict__ Bl,
        const float* __restrict__ bias,
        ushort_t* __restrict__ Ch, ushort_t* __restrict__ Cl,
        int M, int Nreal, int CW) {
    __shared__ ushort_t AsH[128][40];
    __shared__ ushort_t AsL[128][40];
    __shared__ ushort_t BsH[64][40];
    __shared__ ushort_t BsL[64][40];
    const int tid = threadIdx.x;
    const int row0 = blockIdx.y * 128;
    const int col0 = blockIdx.x * 64;
    const int w  = tid >> 6, l = tid & 63;
    const int wm = w >> 1, wn = w & 1;
    const int lm = l & 15, lq = l >> 4;

    f32x4 acc[4][2];
    #pragma unroll
    for (int i = 0; i < 4; ++i)
        #pragma unroll
        for (int j = 0; j < 2; ++j) acc[i][j] = (f32x4){0.f, 0.f, 0.f, 0.f};

    const int arow  = tid >> 2;         // 0..63
    const int akoff = (tid & 3) * 8;    // 0,8,16,24

    for (int k0 = 0; k0 < KP; k0 += 32) {
        *(int4*)&AsH[arow][akoff]      = *(const int4*)&Ah[(long)(row0 + arow) * KP + k0 + akoff];
        *(int4*)&AsH[arow + 64][akoff] = *(const int4*)&Ah[(long)(row0 + arow + 64) * KP + k0 + akoff];
        *(int4*)&AsL[arow][akoff]      = *(const int4*)&Al[(long)(row0 + arow) * KP + k0 + akoff];
        *(int4*)&AsL[arow + 64][akoff] = *(const int4*)&Al[(long)(row0 + arow + 64) * KP + k0 + akoff];
        *(int4*)&BsH[arow][akoff]      = *(const int4*)&Bh[(long)(col0 + arow) * KP + k0 + akoff];
        *(int4*)&BsL[arow][akoff]      = *(const int4*)&Bl[(long)(col0 + arow) * KP + k0 + akoff];
        __syncthreads();

        bf16x8 afh[4], afl[4], bfh[2], bfl[2];
        #pragma unroll
        for (int ms = 0; ms < 4; ++ms) {
            afh[ms] = *(const bf16x8*)&AsH[wm * 64 + ms * 16 + lm][lq * 8];
            afl[ms] = *(const bf16x8*)&AsL[wm * 64 + ms * 16 + lm][lq * 8];
        }
        #pragma unroll
        for (int ns = 0; ns < 2; ++ns) {
            bfh[ns] = *(const bf16x8*)&BsH[wn * 32 + ns * 16 + lm][lq * 8];
            bfl[ns] = *(const bf16x8*)&BsL[wn * 32 + ns * 16 + lm][lq * 8];
        }
        #pragma unroll
        for (int ms = 0; ms < 4; ++ms)
            #pragma unroll
            for (int ns = 0; ns < 2; ++ns) {
                acc[ms][ns] = __builtin_amdgcn_mfma_f32_16x16x32_bf16(afh[ms], bfh[ns], acc[ms][ns], 0, 0, 0);
                acc[ms][ns] = __builtin_amdgcn_mfma_f32_16x16x32_bf16(afh[ms], bfl[ns], acc[ms][ns], 0, 0, 0);
                acc[ms][ns] = __builtin_amdgcn_mfma_f32_16x16x32_bf16(afl[ms], bfh[ns], acc[ms][ns], 0, 0, 0);
            }
        __syncthreads();
    }

    // epilogue: C/D layout col=lane&15, row=(lane>>4)*4+i  [m89/m91 verified]
    #pragma unroll
    for (int ms = 0; ms < 4; ++ms) {
        int R = row0 + wm * 64 + ms * 16 + lq * 4;
        #pragma unroll
        for (int ns = 0; ns < 2; ++ns) {
            int col = col0 + wn * 32 + ns * 16 + lm;
            if (EPI == 1) {
                if (col < CW) {
                    float bb = (col < Nreal) ? bias[col] : 0.0f;
                    #pragma unroll
                    for (int i = 0; i < 4; ++i) {
                        int row = R + i;
                        if (row < M) {
                            float r = (col < Nreal) ? fmaxf(acc[ms][ns][i] + bb, 0.0f) : 0.0f;
                            ushort_t h = bf16_rne(r);
                            ushort_t lo = bf16_rne(r - bf16_tof(h));
                            Ch[(long)row * CW + col] = h;
                            Cl[(long)row * CW + col] = lo;
                        }
                    }
                }
            } else {
                if (col < Nreal) {
                    #pragma unroll
                    for (int i = 0; i < 4; ++i) {
                        int row = R + i;
                        if (row < M) {
                            __half hv = __float2half_rn(acc[ms][ns][i]);
                            Ch[(long)row * Nreal + col] = *(ushort_t*)&hv;
                        }
                    }
                }
            }
        }
    }
}

// ---------------- agg layer 2 (fp16 gather) + bias + relu ----------------
__global__ __launch_bounds__(256) void k_agg2(const ushort_t* __restrict__ T16,
                                              const int* __restrict__ off,
                                              const int2* __restrict__ csr,
                                              const float* __restrict__ dinv,
                                              const float* __restrict__ b2,
                                              float* __restrict__ out2) {
    int gw = (blockIdx.x * 256 + threadIdx.x) >> 6;
    int lane = threadIdx.x & 63;
    if (gw >= N_NODES) return;
    const int v = gw;
    const int NV = F2 / 4;        // 42 active lanes, each 4 fp16 (8 B)
    int o0 = off[v], o1 = off[v + 1];
    int n = o1 - o0;
    float di = dinv[v];
    float4 acc = {0, 0, 0, 0};
    if (lane < NV) {
        uint2 u = ((const uint2*)(T16 + (long)v * F2))[lane];
        float2 f0 = __half22float2(*(__half2*)&u.x);
        float2 f1 = __half22float2(*(__half2*)&u.y);
        float s2 = di * di;
        acc.x = f0.x * s2; acc.y = f0.y * s2; acc.z = f1.x * s2; acc.w = f1.y * s2;
    }
    int2 e0, e1; uint2 u0 = {0, 0}, u1 = {0, 0};
    if (n > 0) { e0 = csr[o0];     if (lane < NV) u0 = ((const uint2*)(T16 + (long)e0.x * F2))[lane]; }
    if (n > 1) { e1 = csr[o0 + 1]; if (lane < NV) u1 = ((const uint2*)(T16 + (long)e1.x * F2))[lane]; }
    for (int i = o0 + 2; i < o1; ++i) {
        int2 e2 = csr[i];
        uint2 u2 = {0, 0};
        if (lane < NV) u2 = ((const uint2*)(T16 + (long)e2.x * F2))[lane];
        float c = __int_as_float(e0.y);
        float2 f0 = __half22float2(*(__half2*)&u0.x);
        float2 f1 = __half22float2(*(__half2*)&u0.y);
        acc.x += c * f0.x; acc.y += c * f0.y; acc.z += c * f1.x; acc.w += c * f1.y;
        e0 = e1; u0 = u1; e1 = e2; u1 = u2;
    }
    if (n > 1) {
        float c = __int_as_float(e0.y);
        float2 f0 = __half22float2(*(__half2*)&u0.x);
        float2 f1 = __half22float2(*(__half2*)&u0.y);
        acc.x += c * f0.x; acc.y += c * f0.y; acc.z += c * f1.x; acc.w += c * f1.y;
        e0 = e1; u0 = u1;
    }
    if (n > 0) {
        float c = __int_as_float(e0.y);
        float2 f0 = __half22float2(*(__half2*)&u0.x);
        float2 f1 = __half22float2(*(__half2*)&u0.y);
        acc.x += c * f0.x; acc.y += c * f0.y; acc.z += c * f1.x; acc.w += c * f1.y;
    }
    if (lane < NV) {
        float4 bb = ((const float4*)b2)[lane];
        acc.x = fmaxf(acc.x + bb.x, 0.0f);
        acc.y = fmaxf(acc.y + bb.y, 0.0f);
        acc.z = fmaxf(acc.z + bb.z, 0.0f);
        acc.w = fmaxf(acc.w + bb.w, 0.0f);
        ((float4*)(out2 + (long)v * F2))[lane] = acc;
    }
}

// ---------------- per-graph max pool ----------------
__global__ __launch_bounds__(256) void k_pool(const float* __restrict__ out2,
                                              const int* __restrict__ r0,
                                              const int* __restrict__ r1,
                                              float* __restrict__ g) {
    __shared__ float4 sm[4][F2 / 4];
    int gi = blockIdx.x;
    int slot = threadIdx.x >> 6, lane = threadIdx.x & 63;
    int a = r0[gi], b = r1[gi];
    if (lane < F2 / 4) {
        float4 mx = {0, 0, 0, 0};
        for (int v = a + slot; v < b; v += 4) {
            float4 t = ((const float4*)(out2 + (long)v * F2))[lane];
            mx.x = fmaxf(mx.x, t.x); mx.y = fmaxf(mx.y, t.y);
            mx.z = fmaxf(mx.z, t.z); mx.w = fmaxf(mx.w, t.w);
        }
        sm[slot][lane] = mx;
    }
    __syncthreads();
    if (slot == 0 && lane < F2 / 4) {
        float4 m0 = sm[0][lane], m1 = sm[1][lane], m2 = sm[2][lane], m3 = sm[3][lane];
        float4 r;
        r.x = fmaxf(fmaxf(m0.x, m1.x), fmaxf(m2.x, m3.x));
        r.y = fmaxf(fmaxf(m0.y, m1.y), fmaxf(m2.y, m3.y));
        r.z = fmaxf(fmaxf(m0.z, m1.z), fmaxf(m2.z, m3.z));
        r.w = fmaxf(fmaxf(m0.w, m1.w), fmaxf(m2.w, m3.w));
        ((float4*)(g + (long)gi * F2))[lane] = r;
    }
}

// ---------------- MLP head ----------------
__global__ __launch_bounds__(128) void k_mlp_head(const float* __restrict__ g,
        const float* __restrict__ Wg, const float* __restrict__ bg,
        const float* __restrict__ Wf, const float* __restrict__ bf,
        const float* __restrict__ Wo, const float* __restrict__ bo,
        float* __restrict__ out) {
    __shared__ float s0[F2];
    __shared__ float s1[84];
    __shared__ float s2[42];
    int gi = blockIdx.x;
    int t = threadIdx.x;
    for (int i = t; i < F2; i += blockDim.x) s0[i] = g[(long)gi * F2 + i];
    __syncthreads();
    if (t < 84) {
        float a = bg[t];
        #pragma unroll 4
        for (int k = 0; k < F2; ++k) a += s0[k] * Wg[k * 84 + t];
        s1[t] = fmaxf(a, 0.0f);
    }
    __syncthreads();
    if (t < 42) {
        float a = bf[t];
        #pragma unroll 4
        for (int k = 0; k < 84; ++k) a += s1[k] * Wf[k * 42 + t];
        s2[t] = fmaxf(a, 0.0f);
    }
    __syncthreads();
    if (t == 0) {
        float a = bo[0];
        for (int k = 0; k < 42; ++k) a += s2[k] * Wo[k];
        out[gi] = a;
    }
}

extern "C" void kernel_launch(void* const* d_in, const int* in_sizes, int n_in,
                              void* d_out, int out_size, void* d_ws, size_t ws_size,
                              hipStream_t stream) {
    const float* x   = (const float*)d_in[0];
    const int*   ei  = (const int*)d_in[1];
    const int*   bat = (const int*)d_in[2];
    const float* W1  = (const float*)d_in[3];
    const float* b1  = (const float*)d_in[4];
    const float* W2  = (const float*)d_in[5];
    const float* b2  = (const float*)d_in[6];
    const float* Wg  = (const float*)d_in[7];
    const float* bg  = (const float*)d_in[8];
    const float* Wf  = (const float*)d_in[9];
    const float* bf  = (const float*)d_in[10];
    const float* Wo  = (const float*)d_in[11];
    const float* bo  = (const float*)d_in[12];
    float* out = (float*)d_out;

    // ---- workspace carve-up (every chunk 16B-aligned; dcount+cur adjacent) ----
    char* p = (char*)d_ws;
    float* dinv     = (float*)p; p += 50048 * 4;
    int*   dcount   = (int*)p;   p += 50048 * 4;
    int*   cur      = (int*)p;   p += 50048 * 4;
    int*   off      = (int*)p;   p += 50064 * 4;
    int*   partials = (int*)p;   p += 64 * 4;
    int*   rng0     = (int*)p;   p += 256 * 4;
    int*   rng1     = (int*)p;   p += 256 * 4;
    int2*  csr      = (int2*)p;  p += (long)N_EDGES * 8;
    ushort_t* x16   = (ushort_t*)p; p += (long)N_NODES * F_IN * 2;   // fp16 X
    ushort_t* aXh   = (ushort_t*)p; p += (long)MPAD * K1P * 2;
    ushort_t* aXl   = (ushort_t*)p; p += (long)MPAD * K1P * 2;
    ushort_t* w1th  = (ushort_t*)p; p += (long)384 * K1P * 2;
    ushort_t* w1tl  = (ushort_t*)p; p += (long)384 * K1P * 2;
    ushort_t* w2th  = (ushort_t*)p; p += (long)192 * K2P * 2;
    ushort_t* w2tl  = (ushort_t*)p; p += (long)192 * K2P * 2;
    ushort_t* h1h   = (ushort_t*)p; p += (long)MPAD * K2P * 2;
    ushort_t* h1l   = (ushort_t*)p; p += (long)MPAD * K2P * 2;
    ushort_t* t16   = (ushort_t*)p; p += (long)N_NODES * F2 * 2;     // fp16 T2
    float* out2     = (float*)p; p += (long)N_NODES * F2 * 4;
    float* g        = (float*)p; p += (long)NGRAPH * F2 * 4;

    const int* src = ei;
    const int* dst = ei + N_EDGES;
    const int B = 256;

    // ---- degrees, dinv, ranges, X->fp16 ----
    k_zero_int<<<(2 * 50048 + B - 1) / B, B, 0, stream>>>(dcount, 2 * 50048);  // dcount+cur
    k_count_deg<<<(N_EDGES + B - 1) / B, B, 0, stream>>>(dst, dcount, N_EDGES);
    k_dinv<<<(N_NODES + B - 1) / B, B, 0, stream>>>(dcount, dinv, N_NODES);
    k_ranges<<<(N_NODES + B - 1) / B, B, 0, stream>>>(bat, rng0, rng1, N_NODES);
    k_cvtX<<<(N_NODES * (F_IN / 4) + B - 1) / B, B, 0, stream>>>(x, x16, N_NODES * (F_IN / 4));

    // ---- scan -> off ----
    k_scan1<<<SCAN_BLOCKS, SCAN_CHUNK, 0, stream>>>(dcount, off, partials, N_NODES);
    k_scan2<<<1, 64, 0, stream>>>(partials, off, SCAN_BLOCKS, N_NODES);
    k_scan3<<<SCAN_BLOCKS, SCAN_CHUNK, 0, stream>>>(off, partials, N_NODES);

    // ---- scatter CSR ----
    k_scatter<<<(N_EDGES + B - 1) / B, B, 0, stream>>>(src, dst, off, cur, dinv, csr, N_EDGES);

    // ---- weight transpose+split ----
    k_cvtW<F_IN, F1, K1P, 384><<<(384 * K1P + 255) / 256, 256, 0, stream>>>(W1, w1th, w1tl);
    k_cvtW<F1, F2, K2P, 192><<<(192 * K2P + 255) / 256, 256, 0, stream>>>(W2, w2th, w2tl);

    // ---- layer 1 ----
    k_agg1<<<(N_NODES * 64 + 255) / 256, 256, 0, stream>>>(x16, off, csr, dinv, aXh, aXl);
    dim3 gg1(6, MPAD / 128);
    k_gemm_mfma<K1P, 1><<<gg1, 256, 0, stream>>>(aXh, aXl, w1th, w1tl, b1,
                                                 h1h, h1l, N_NODES, F1, K2P);

    // ---- layer 2 ----
    dim3 gg2(3, MPAD / 128);
    k_gemm_mfma<K2P, 2><<<gg2, 256, 0, stream>>>(h1h, h1l, w2th, w2tl, nullptr,
                                                 t16, nullptr, N_NODES, F2, 0);
    k_agg2<<<(N_NODES * 64 + 255) / 256, 256, 0, stream>>>(t16, off, csr, dinv, b2, out2);

    // ---- pool + head ----
    k_pool<<<NGRAPH, 256, 0, stream>>>(out2, rng0, rng1, g);
    k_mlp_head<<<NGRAPH, 128, 0, stream>>>(g, Wg, bg, Wf, bf, Wo, bo, out);
}

// Round 7
// 337.200 us; speedup vs baseline: 1.2764x; 1.2764x over previous
//
#include <hip/hip_runtime.h>
#include <hip/hip_fp16.h>

#define N_NODES 50000
#define MPAD    50048            // 391 * 128
#define N_EDGES 500000
#define F_IN    112
#define K1P     128              // F_IN padded to 32-multiple
#define F1      336
#define K2P     352              // F1 padded to 32-multiple
#define F2      168
#define NGRAPH  256
#define SCAN_CHUNK 1024
#define SCAN_BLOCKS ((N_NODES + SCAN_CHUNK - 1) / SCAN_CHUNK)   // 49

typedef __attribute__((ext_vector_type(8))) _Float16 f16x8;
typedef __attribute__((ext_vector_type(4))) float f32x4;
typedef unsigned short ushort_t;

__device__ __forceinline__ ushort_t f16_bits(float x) {
    __half h = __float2half_rn(x);
    return *(ushort_t*)&h;
}

// ---------------- small utility kernels ----------------
__global__ void k_zero_int(int* p, int n) {
    int i = blockIdx.x * blockDim.x + threadIdx.x;
    if (i < n) p[i] = 0;
}
__global__ void k_count_deg(const int* __restrict__ dst, int* __restrict__ dcount, int e) {
    int i = blockIdx.x * blockDim.x + threadIdx.x;
    if (i < e) atomicAdd(&dcount[dst[i]], 1);
}

// ---------------- fused prep: cvtX | cvtW1 | cvtW2 | ranges (one launch) ----------------
#define CVX_BLOCKS  ((N_NODES * (F_IN / 4) + 255) / 256)   // 5469
#define CVW1_BLOCKS ((384 * K1P + 255) / 256)              // 192
#define CVW2_BLOCKS ((192 * K2P + 255) / 256)              // 264
#define RNG_BLOCKS  ((N_NODES + 255) / 256)                // 196
#define PREP_BLOCKS (CVX_BLOCKS + CVW1_BLOCKS + CVW2_BLOCKS + RNG_BLOCKS)

__global__ __launch_bounds__(256) void k_prep(const float* __restrict__ x,
                                              const float* __restrict__ W1,
                                              const float* __restrict__ W2,
                                              const int* __restrict__ batch,
                                              ushort_t* __restrict__ x16,
                                              ushort_t* __restrict__ w1t,
                                              ushort_t* __restrict__ w2t,
                                              int* __restrict__ r0, int* __restrict__ r1) {
    int bid = blockIdx.x;
    int t = threadIdx.x;
    if (bid < CVX_BLOCKS) {                       // X fp32 -> fp16, 4/thread
        int i = bid * 256 + t;
        if (i < N_NODES * (F_IN / 4)) {
            float4 v = ((const float4*)x)[i];
            __half2 h0 = __floats2half2_rn(v.x, v.y);
            __half2 h1 = __floats2half2_rn(v.z, v.w);
            uint2 u; u.x = *(unsigned*)&h0; u.y = *(unsigned*)&h1;
            ((uint2*)x16)[i] = u;
        }
        return;
    }
    bid -= CVX_BLOCKS;
    if (bid < CVW1_BLOCKS) {                      // W1[K,N] -> w1t[n][k] fp16
        int idx = bid * 256 + t;
        if (idx < 384 * K1P) {
            int n = idx / K1P, k = idx % K1P;
            float v = (n < F1 && k < F_IN) ? W1[k * F1 + n] : 0.0f;
            w1t[idx] = f16_bits(v);
        }
        return;
    }
    bid -= CVW1_BLOCKS;
    if (bid < CVW2_BLOCKS) {                      // W2[K,N] -> w2t[n][k] fp16
        int idx = bid * 256 + t;
        if (idx < 192 * K2P) {
            int n = idx / K2P, k = idx % K2P;
            float v = (n < F2 && k < F1) ? W2[k * F2 + n] : 0.0f;
            w2t[idx] = f16_bits(v);
        }
        return;
    }
    bid -= CVW2_BLOCKS;
    {                                             // per-graph ranges (batch sorted)
        int v = bid * 256 + t;
        if (v >= N_NODES) return;
        int b = batch[v];
        if (v == 0 || batch[v - 1] != b) r0[b] = v;
        if (v == N_NODES - 1 || batch[v + 1] != b) r1[b] = v + 1;
    }
}

// ---------------- exclusive scan of dcount -> off (dinv fused into pass 1) ----------------
__global__ __launch_bounds__(SCAN_CHUNK) void k_scan1(const int* __restrict__ dcount,
                                                      int* __restrict__ off,
                                                      int* __restrict__ partials,
                                                      float* __restrict__ dinv, int n) {
    __shared__ int s[SCAN_CHUNK];
    int t = threadIdx.x;
    int i = blockIdx.x * SCAN_CHUNK + t;
    int val = (i < n) ? dcount[i] : 0;
    s[t] = val;
    __syncthreads();
    for (int d = 1; d < SCAN_CHUNK; d <<= 1) {
        int x = (t >= d) ? s[t - d] : 0;
        __syncthreads();
        s[t] += x;
        __syncthreads();
    }
    if (i < n) {
        off[i] = s[t] - val;
        dinv[i] = rsqrtf((float)val + 1.0f);      // +1 self-loop
    }
    if (t == SCAN_CHUNK - 1) partials[blockIdx.x] = s[t];
}
__global__ void k_scan2(int* __restrict__ partials, int* __restrict__ off, int nblk, int n) {
    if (threadIdx.x == 0 && blockIdx.x == 0) {
        int run = 0;
        for (int j = 0; j < nblk; ++j) { int p = partials[j]; partials[j] = run; run += p; }
        off[n] = run;
    }
}
__global__ __launch_bounds__(SCAN_CHUNK) void k_scan3(int* __restrict__ off,
                                                      const int* __restrict__ partials, int n) {
    int i = blockIdx.x * SCAN_CHUNK + threadIdx.x;
    if (i < n) off[i] += partials[blockIdx.x];
}

// ---------------- scatter edges into dst-sorted CSR, packed (src, coef) ----------------
__global__ void k_scatter(const int* __restrict__ src, const int* __restrict__ dst,
                          const int* __restrict__ off, int* __restrict__ cur,
                          const float* __restrict__ dinv,
                          int2* __restrict__ csr, int e) {
    int i = blockIdx.x * blockDim.x + threadIdx.x;
    if (i >= e) return;
    int s = src[i], d = dst[i];
    int pos = atomicAdd(&cur[d], 1);
    int2 rec;
    rec.x = s;
    rec.y = __float_as_int(dinv[s] * dinv[d]);
    csr[off[d] + pos] = rec;
}

// ---------------- agg layer 1: A_norm @ X16 -> fp16 [MPAD][K1P], depth-8 batched ----------------
__global__ __launch_bounds__(256) void k_agg1(const ushort_t* __restrict__ X16,
                                              const int* __restrict__ off,
                                              const int2* __restrict__ csr,
                                              const float* __restrict__ dinv,
                                              ushort_t* __restrict__ aX) {
    int gw = (blockIdx.x * 256 + threadIdx.x) >> 6;
    int lane = threadIdx.x & 63;
    if (gw >= N_NODES) return;
    const int v = gw;
    const int NV = F_IN / 2;      // 56 active lanes, 2 fp16 each
    const bool act = lane < NV;
    int o0 = off[v], o1 = off[v + 1];
    float di = dinv[v];
    float2 acc = {0.0f, 0.0f};
    if (act) {
        float2 xv = __half22float2(((const __half2*)(X16 + (long)v * F_IN))[lane]);
        float s2 = di * di;
        acc.x = xv.x * s2; acc.y = xv.y * s2;
    }
    for (int b = o0; b < o1; b += 8) {
        int m = o1 - b; if (m > 8) m = 8;
        int2 e[8];
        #pragma unroll
        for (int j = 0; j < 8; ++j) if (j < m) e[j] = csr[b + j];
        unsigned u[8];
        #pragma unroll
        for (int j = 0; j < 8; ++j)
            if (j < m && act) u[j] = ((const unsigned*)(X16 + (long)e[j].x * F_IN))[lane];
        #pragma unroll
        for (int j = 0; j < 8; ++j)
            if (j < m) {
                float c = __int_as_float(e[j].y);
                float2 tv = __half22float2(*(__half2*)&u[j]);
                acc.x += c * tv.x; acc.y += c * tv.y;
            }
    }
    unsigned vh = 0;
    if (act) { __half2 h = __floats2half2_rn(acc.x, acc.y); vh = *(unsigned*)&h; }
    ((unsigned*)(aX + (long)v * K1P))[lane] = vh;   // lanes 56..63 zero the K pad
}

// ---------------- fp16 MFMA GEMM: C = A[M,KP] @ Bt[N,KP]^T ----------------
// 128x64 tile, 4 waves (2x2), 16x16x32 f16 MFMA, 1 MFMA per (ms,ns) per k-step.
// EPI==1: C -> fp16 width CW, relu(acc+bias) for col<Nreal, 0 pad beyond
// EPI==2: C -> fp16 width Nreal
template<int KP, int EPI>
__global__ __launch_bounds__(256) void k_gemm_f16(
        const ushort_t* __restrict__ A, const ushort_t* __restrict__ Bt,
        const float* __restrict__ bias,
        ushort_t* __restrict__ C, int M, int Nreal, int CW) {
    __shared__ ushort_t As[128][40];   // 80 B rows (16B-aligned), 2-way bank alias (free)
    __shared__ ushort_t Bs[64][40];
    const int tid = threadIdx.x;
    const int row0 = blockIdx.y * 128;
    const int col0 = blockIdx.x * 64;
    const int w  = tid >> 6, l = tid & 63;
    const int wm = w >> 1, wn = w & 1;
    const int lm = l & 15, lq = l >> 4;

    f32x4 acc[4][2];
    #pragma unroll
    for (int i = 0; i < 4; ++i)
        #pragma unroll
        for (int j = 0; j < 2; ++j) acc[i][j] = (f32x4){0.f, 0.f, 0.f, 0.f};

    const int arow  = tid >> 2;         // 0..63
    const int akoff = (tid & 3) * 8;    // 0,8,16,24

    for (int k0 = 0; k0 < KP; k0 += 32) {
        *(int4*)&As[arow][akoff]      = *(const int4*)&A[(long)(row0 + arow) * KP + k0 + akoff];
        *(int4*)&As[arow + 64][akoff] = *(const int4*)&A[(long)(row0 + arow + 64) * KP + k0 + akoff];
        *(int4*)&Bs[arow][akoff]      = *(const int4*)&Bt[(long)(col0 + arow) * KP + k0 + akoff];
        __syncthreads();

        f16x8 af[4], bf[2];
        #pragma unroll
        for (int ms = 0; ms < 4; ++ms)
            af[ms] = *(const f16x8*)&As[wm * 64 + ms * 16 + lm][lq * 8];
        #pragma unroll
        for (int ns = 0; ns < 2; ++ns)
            bf[ns] = *(const f16x8*)&Bs[wn * 32 + ns * 16 + lm][lq * 8];
        #pragma unroll
        for (int ms = 0; ms < 4; ++ms)
            #pragma unroll
            for (int ns = 0; ns < 2; ++ns)
                acc[ms][ns] = __builtin_amdgcn_mfma_f32_16x16x32_f16(af[ms], bf[ns], acc[ms][ns], 0, 0, 0);
        __syncthreads();
    }

    // epilogue: C/D layout col=lane&15, row=(lane>>4)*4+i  [m89/m91 verified]
    #pragma unroll
    for (int ms = 0; ms < 4; ++ms) {
        int R = row0 + wm * 64 + ms * 16 + lq * 4;
        #pragma unroll
        for (int ns = 0; ns < 2; ++ns) {
            int col = col0 + wn * 32 + ns * 16 + lm;
            if (EPI == 1) {
                if (col < CW) {
                    float bb = (col < Nreal) ? bias[col] : 0.0f;
                    #pragma unroll
                    for (int i = 0; i < 4; ++i) {
                        int row = R + i;
                        if (row < M) {
                            float r = (col < Nreal) ? fmaxf(acc[ms][ns][i] + bb, 0.0f) : 0.0f;
                            C[(long)row * CW + col] = f16_bits(r);
                        }
                    }
                }
            } else {
                if (col < Nreal) {
                    #pragma unroll
                    for (int i = 0; i < 4; ++i) {
                        int row = R + i;
                        if (row < M) C[(long)row * Nreal + col] = f16_bits(acc[ms][ns][i]);
                    }
                }
            }
        }
    }
}

// ---------------- agg layer 2 (fp16 gather, depth-8) + bias + relu -> fp16 out2 ----------------
__global__ __launch_bounds__(256) void k_agg2(const ushort_t* __restrict__ T16,
                                              const int* __restrict__ off,
                                              const int2* __restrict__ csr,
                                              const float* __restrict__ dinv,
                                              const float* __restrict__ b2,
                                              ushort_t* __restrict__ out2) {
    int gw = (blockIdx.x * 256 + threadIdx.x) >> 6;
    int lane = threadIdx.x & 63;
    if (gw >= N_NODES) return;
    const int v = gw;
    const int NV = F2 / 4;        // 42 active lanes, 4 fp16 (8 B) each
    const bool act = lane < NV;
    int o0 = off[v], o1 = off[v + 1];
    float di = dinv[v];
    float4 acc = {0, 0, 0, 0};
    if (act) {
        uint2 u = ((const uint2*)(T16 + (long)v * F2))[lane];
        float2 f0 = __half22float2(*(__half2*)&u.x);
        float2 f1 = __half22float2(*(__half2*)&u.y);
        float s2 = di * di;
        acc.x = f0.x * s2; acc.y = f0.y * s2; acc.z = f1.x * s2; acc.w = f1.y * s2;
    }
    for (int b = o0; b < o1; b += 8) {
        int m = o1 - b; if (m > 8) m = 8;
        int2 e[8];
        #pragma unroll
        for (int j = 0; j < 8; ++j) if (j < m) e[j] = csr[b + j];
        uint2 u[8];
        #pragma unroll
        for (int j = 0; j < 8; ++j)
            if (j < m && act) u[j] = ((const uint2*)(T16 + (long)e[j].x * F2))[lane];
        #pragma unroll
        for (int j = 0; j < 8; ++j)
            if (j < m) {
                float c = __int_as_float(e[j].y);
                float2 f0 = __half22float2(*(__half2*)&u[j].x);
                float2 f1 = __half22float2(*(__half2*)&u[j].y);
                acc.x += c * f0.x; acc.y += c * f0.y; acc.z += c * f1.x; acc.w += c * f1.y;
            }
    }
    if (act) {
        float4 bb = ((const float4*)b2)[lane];
        __half2 h0 = __floats2half2_rn(fmaxf(acc.x + bb.x, 0.0f), fmaxf(acc.y + bb.y, 0.0f));
        __half2 h1 = __floats2half2_rn(fmaxf(acc.z + bb.z, 0.0f), fmaxf(acc.w + bb.w, 0.0f));
        uint2 o; o.x = *(unsigned*)&h0; o.y = *(unsigned*)&h1;
        ((uint2*)(out2 + (long)v * F2))[lane] = o;
    }
}

// ---------------- per-graph max pool (fp16 in, fp32 out) ----------------
__global__ __launch_bounds__(256) void k_pool(const ushort_t* __restrict__ out2,
                                              const int* __restrict__ r0,
                                              const int* __restrict__ r1,
                                              float* __restrict__ g) {
    __shared__ float4 sm[4][F2 / 4];
    int gi = blockIdx.x;
    int slot = threadIdx.x >> 6, lane = threadIdx.x & 63;
    int a = r0[gi], b = r1[gi];
    if (lane < F2 / 4) {
        float4 mx = {0, 0, 0, 0};    // post-relu values >= 0
        for (int v = a + slot; v < b; v += 4) {
            uint2 u = ((const uint2*)(out2 + (long)v * F2))[lane];
            float2 f0 = __half22float2(*(__half2*)&u.x);
            float2 f1 = __half22float2(*(__half2*)&u.y);
            mx.x = fmaxf(mx.x, f0.x); mx.y = fmaxf(mx.y, f0.y);
            mx.z = fmaxf(mx.z, f1.x); mx.w = fmaxf(mx.w, f1.y);
        }
        sm[slot][lane] = mx;
    }
    __syncthreads();
    if (slot == 0 && lane < F2 / 4) {
        float4 m0 = sm[0][lane], m1 = sm[1][lane], m2 = sm[2][lane], m3 = sm[3][lane];
        float4 r;
        r.x = fmaxf(fmaxf(m0.x, m1.x), fmaxf(m2.x, m3.x));
        r.y = fmaxf(fmaxf(m0.y, m1.y), fmaxf(m2.y, m3.y));
        r.z = fmaxf(fmaxf(m0.z, m1.z), fmaxf(m2.z, m3.z));
        r.w = fmaxf(fmaxf(m0.w, m1.w), fmaxf(m2.w, m3.w));
        ((float4*)(g + (long)gi * F2))[lane] = r;
    }
}

// ---------------- MLP head ----------------
__global__ __launch_bounds__(128) void k_mlp_head(const float* __restrict__ g,
        const float* __restrict__ Wg, const float* __restrict__ bg,
        const float* __restrict__ Wf, const float* __restrict__ bf,
        const float* __restrict__ Wo, const float* __restrict__ bo,
        float* __restrict__ out) {
    __shared__ float s0[F2];
    __shared__ float s1[84];
    __shared__ float s2[42];
    int gi = blockIdx.x;
    int t = threadIdx.x;
    for (int i = t; i < F2; i += blockDim.x) s0[i] = g[(long)gi * F2 + i];
    __syncthreads();
    if (t < 84) {
        float a = bg[t];
        #pragma unroll 4
        for (int k = 0; k < F2; ++k) a += s0[k] * Wg[k * 84 + t];
        s1[t] = fmaxf(a, 0.0f);
    }
    __syncthreads();
    if (t < 42) {
        float a = bf[t];
        #pragma unroll 4
        for (int k = 0; k < 84; ++k) a += s1[k] * Wf[k * 42 + t];
        s2[t] = fmaxf(a, 0.0f);
    }
    __syncthreads();
    if (t == 0) {
        float a = bo[0];
        for (int k = 0; k < 42; ++k) a += s2[k] * Wo[k];
        out[gi] = a;
    }
}

extern "C" void kernel_launch(void* const* d_in, const int* in_sizes, int n_in,
                              void* d_out, int out_size, void* d_ws, size_t ws_size,
                              hipStream_t stream) {
    const float* x   = (const float*)d_in[0];
    const int*   ei  = (const int*)d_in[1];
    const int*   bat = (const int*)d_in[2];
    const float* W1  = (const float*)d_in[3];
    const float* b1  = (const float*)d_in[4];
    const float* W2  = (const float*)d_in[5];
    const float* b2  = (const float*)d_in[6];
    const float* Wg  = (const float*)d_in[7];
    const float* bg  = (const float*)d_in[8];
    const float* Wf  = (const float*)d_in[9];
    const float* bf  = (const float*)d_in[10];
    const float* Wo  = (const float*)d_in[11];
    const float* bo  = (const float*)d_in[12];
    float* out = (float*)d_out;

    // ---- workspace carve-up (16B-aligned chunks; dcount+cur adjacent for one memset) ----
    char* p = (char*)d_ws;
    float* dinv     = (float*)p; p += 50048 * 4;
    int*   dcount   = (int*)p;   p += 50048 * 4;
    int*   cur      = (int*)p;   p += 50048 * 4;
    int*   off      = (int*)p;   p += 50064 * 4;
    int*   partials = (int*)p;   p += 64 * 4;
    int*   rng0     = (int*)p;   p += 256 * 4;
    int*   rng1     = (int*)p;   p += 256 * 4;
    int2*  csr      = (int2*)p;  p += (long)N_EDGES * 8;
    ushort_t* x16   = (ushort_t*)p; p += (long)N_NODES * F_IN * 2;
    ushort_t* aX    = (ushort_t*)p; p += (long)MPAD * K1P * 2;       // fp16 A@X
    ushort_t* w1t   = (ushort_t*)p; p += (long)384 * K1P * 2;
    ushort_t* w2t   = (ushort_t*)p; p += (long)192 * K2P * 2;
    ushort_t* h1    = (ushort_t*)p; p += (long)MPAD * K2P * 2;       // fp16 H1
    ushort_t* t16   = (ushort_t*)p; p += (long)N_NODES * F2 * 2;     // fp16 T2
    ushort_t* o16   = (ushort_t*)p; p += (long)N_NODES * F2 * 2;     // fp16 out2
    float* g        = (float*)p; p += (long)NGRAPH * F2 * 4;

    const int* src = ei;
    const int* dst = ei + N_EDGES;
    const int B = 256;

    // ---- preproc ----
    k_zero_int<<<(2 * 50048 + B - 1) / B, B, 0, stream>>>(dcount, 2 * 50048);  // dcount+cur
    k_count_deg<<<(N_EDGES + B - 1) / B, B, 0, stream>>>(dst, dcount, N_EDGES);
    k_prep<<<PREP_BLOCKS, B, 0, stream>>>(x, W1, W2, bat, x16, w1t, w2t, rng0, rng1);
    k_scan1<<<SCAN_BLOCKS, SCAN_CHUNK, 0, stream>>>(dcount, off, partials, dinv, N_NODES);
    k_scan2<<<1, 64, 0, stream>>>(partials, off, SCAN_BLOCKS, N_NODES);
    k_scan3<<<SCAN_BLOCKS, SCAN_CHUNK, 0, stream>>>(off, partials, N_NODES);
    k_scatter<<<(N_EDGES + B - 1) / B, B, 0, stream>>>(src, dst, off, cur, dinv, csr, N_EDGES);

    // ---- layer 1 ----
    k_agg1<<<(N_NODES * 64 + 255) / 256, 256, 0, stream>>>(x16, off, csr, dinv, aX);
    dim3 gg1(6, MPAD / 128);   // 384/64 x 391
    k_gemm_f16<K1P, 1><<<gg1, 256, 0, stream>>>(aX, w1t, b1, h1, N_NODES, F1, K2P);

    // ---- layer 2 ----
    dim3 gg2(3, MPAD / 128);   // 192/64 x 391
    k_gemm_f16<K2P, 2><<<gg2, 256, 0, stream>>>(h1, w2t, nullptr, t16, N_NODES, F2, 0);
    k_agg2<<<(N_NODES * 64 + 255) / 256, 256, 0, stream>>>(t16, off, csr, dinv, b2, o16);

    // ---- pool + head ----
    k_pool<<<NGRAPH, 256, 0, stream>>>(o16, rng0, rng1, g);
    k_mlp_head<<<NGRAPH, 128, 0, stream>>>(g, Wg, bg, Wf, bf, Wo, bo, out);
}

// Round 8
// 299.438 us; speedup vs baseline: 1.4374x; 1.1261x over previous
//
#include <hip/hip_runtime.h>
#include <hip/hip_fp16.h>

#define N_NODES 50000
#define MPAD    50048            // 391 * 128
#define N_EDGES 500000
#define F_IN    112
#define K1P     128              // F_IN padded to 32-multiple
#define F1      336
#define K2P     352              // F1 padded to 32-multiple
#define F2      168
#define NGRAPH  256
#define SCAN_CHUNK 1024
#define SCAN_BLOCKS ((N_NODES + SCAN_CHUNK - 1) / SCAN_CHUNK)   // 49

typedef __attribute__((ext_vector_type(8))) _Float16 f16x8;
typedef __attribute__((ext_vector_type(4))) float f32x4;
typedef unsigned short ushort_t;

__device__ __forceinline__ ushort_t f16_bits(float x) {
    __half h = __float2half_rn(x);
    return *(ushort_t*)&h;
}

// ---------------- small utility kernels ----------------
__global__ void k_zero_int(int* p, int n) {
    int i = blockIdx.x * blockDim.x + threadIdx.x;
    if (i < n) p[i] = 0;
}
__global__ void k_count_deg(const int* __restrict__ dst, int* __restrict__ dcount, int e2) {
    int i = blockIdx.x * blockDim.x + threadIdx.x;
    if (i < e2) {
        int2 d = ((const int2*)dst)[i];
        atomicAdd(&dcount[d.x], 1);
        atomicAdd(&dcount[d.y], 1);
    }
}

// ---------------- fused prep: cvtX | cvtW1 | cvtW2 | ranges (one launch) ----------------
#define CVX_BLOCKS  ((N_NODES * (F_IN / 4) + 255) / 256)   // 5469
#define CVW1_BLOCKS ((384 * K1P + 255) / 256)              // 192
#define CVW2_BLOCKS ((192 * K2P + 255) / 256)              // 264
#define RNG_BLOCKS  ((N_NODES + 255) / 256)                // 196
#define PREP_BLOCKS (CVX_BLOCKS + CVW1_BLOCKS + CVW2_BLOCKS + RNG_BLOCKS)

__global__ __launch_bounds__(256) void k_prep(const float* __restrict__ x,
                                              const float* __restrict__ W1,
                                              const float* __restrict__ W2,
                                              const int* __restrict__ batch,
                                              ushort_t* __restrict__ x16,
                                              ushort_t* __restrict__ w1t,
                                              ushort_t* __restrict__ w2t,
                                              int* __restrict__ r0, int* __restrict__ r1) {
    int bid = blockIdx.x;
    int t = threadIdx.x;
    if (bid < CVX_BLOCKS) {                       // X fp32 -> fp16, 4/thread
        int i = bid * 256 + t;
        if (i < N_NODES * (F_IN / 4)) {
            float4 v = ((const float4*)x)[i];
            __half2 h0 = __floats2half2_rn(v.x, v.y);
            __half2 h1 = __floats2half2_rn(v.z, v.w);
            uint2 u; u.x = *(unsigned*)&h0; u.y = *(unsigned*)&h1;
            ((uint2*)x16)[i] = u;
        }
        return;
    }
    bid -= CVX_BLOCKS;
    if (bid < CVW1_BLOCKS) {                      // W1[K,N] -> w1t[n][k] fp16
        int idx = bid * 256 + t;
        if (idx < 384 * K1P) {
            int n = idx / K1P, k = idx % K1P;
            float v = (n < F1 && k < F_IN) ? W1[k * F1 + n] : 0.0f;
            w1t[idx] = f16_bits(v);
        }
        return;
    }
    bid -= CVW1_BLOCKS;
    if (bid < CVW2_BLOCKS) {                      // W2[K,N] -> w2t[n][k] fp16
        int idx = bid * 256 + t;
        if (idx < 192 * K2P) {
            int n = idx / K2P, k = idx % K2P;
            float v = (n < F2 && k < F1) ? W2[k * F2 + n] : 0.0f;
            w2t[idx] = f16_bits(v);
        }
        return;
    }
    bid -= CVW2_BLOCKS;
    {                                             // per-graph ranges (batch sorted)
        int v = bid * 256 + t;
        if (v >= N_NODES) return;
        int b = batch[v];
        if (v == 0 || batch[v - 1] != b) r0[b] = v;
        if (v == N_NODES - 1 || batch[v + 1] != b) r1[b] = v + 1;
    }
}

// ---------------- scan pass 1 (dinv fused) ----------------
__global__ __launch_bounds__(SCAN_CHUNK) void k_scan1(const int* __restrict__ dcount,
                                                      int* __restrict__ off,
                                                      int* __restrict__ partials,
                                                      float* __restrict__ dinv, int n) {
    __shared__ int s[SCAN_CHUNK];
    int t = threadIdx.x;
    int i = blockIdx.x * SCAN_CHUNK + t;
    int val = (i < n) ? dcount[i] : 0;
    s[t] = val;
    __syncthreads();
    for (int d = 1; d < SCAN_CHUNK; d <<= 1) {
        int x = (t >= d) ? s[t - d] : 0;
        __syncthreads();
        s[t] += x;
        __syncthreads();
    }
    if (i < n) {
        off[i] = s[t] - val;
        dinv[i] = rsqrtf((float)val + 1.0f);      // +1 self-loop
    }
    if (t == SCAN_CHUNK - 1) partials[blockIdx.x] = s[t];
}
// scan pass 2+3 merged: each block redundantly prefixes the 49 partials
__global__ __launch_bounds__(SCAN_CHUNK) void k_scan3(int* __restrict__ off,
                                                      const int* __restrict__ partials, int n) {
    __shared__ int tmp[SCAN_BLOCKS];
    __shared__ int pref[SCAN_BLOCKS];
    int t = threadIdx.x;
    if (t < SCAN_BLOCKS) tmp[t] = partials[t];
    __syncthreads();
    if (t == 0) {
        int run = 0;
        for (int j = 0; j < SCAN_BLOCKS; ++j) { pref[j] = run; run += tmp[j]; }
    }
    __syncthreads();
    int i = blockIdx.x * SCAN_CHUNK + t;
    if (i < n) off[i] += pref[blockIdx.x];
    if (i == n) off[i] = N_EDGES;                 // total degree = E (every edge counted once)
}

// ---------------- scatter edges into dst-sorted CSR, packed (src, coef) ----------------
__global__ void k_scatter(const int* __restrict__ src, const int* __restrict__ dst,
                          const int* __restrict__ off, int* __restrict__ cur,
                          const float* __restrict__ dinv,
                          int2* __restrict__ csr, int e) {
    int i = blockIdx.x * blockDim.x + threadIdx.x;
    if (i >= e) return;
    int s = src[i], d = dst[i];
    int pos = atomicAdd(&cur[d], 1);
    int2 rec;
    rec.x = s;
    rec.y = __float_as_int(dinv[s] * dinv[d]);
    csr[off[d] + pos] = rec;
}

// ---------------- agg layer 1: 2 nodes/wave (half-wave each), depth-8 ----------------
// lanes 0-27: node 2w, lanes 32-59: node 2w+1; uint2 (4 fp16) per lane
__global__ __launch_bounds__(256) void k_agg1(const ushort_t* __restrict__ X16,
                                              const int* __restrict__ off,
                                              const int2* __restrict__ csr,
                                              const float* __restrict__ dinv,
                                              ushort_t* __restrict__ aX) {
    int w = (blockIdx.x * 256 + threadIdx.x) >> 6;
    int lane = threadIdx.x & 63;
    if (w >= N_NODES / 2) return;
    const int g = lane >> 5, sl = lane & 31;
    const int v = 2 * w + g;
    const bool act = sl < 28;                     // 28 lanes x 4 feats = 112
    int o0A = off[2 * w], oM = off[2 * w + 1], o1B = off[2 * w + 2];
    int o0 = g ? oM : o0A;
    int n  = g ? (o1B - oM) : (oM - o0A);
    int nmax = max(oM - o0A, o1B - oM);
    float di = dinv[v];
    float4 acc = {0, 0, 0, 0};
    if (act) {
        uint2 u = *(const uint2*)(X16 + (long)v * F_IN + sl * 4);
        float2 f0 = __half22float2(*(__half2*)&u.x);
        float2 f1 = __half22float2(*(__half2*)&u.y);
        float s2 = di * di;
        acc.x = f0.x * s2; acc.y = f0.y * s2; acc.z = f1.x * s2; acc.w = f1.y * s2;
    }
    int nm1 = max(n - 1, 0);
    for (int b = 0; b < nmax; b += 8) {
        int2 e[8];
        #pragma unroll
        for (int j = 0; j < 8; ++j) {
            int cidx = min(o0 + min(b + j, nm1), N_EDGES - 1);
            e[j] = csr[cidx];                     // uniform per half-wave -> broadcast
        }
        uint2 u[8];
        #pragma unroll
        for (int j = 0; j < 8; ++j) {
            bool valid = (b + j) < n;
            int s = valid ? e[j].x : v;
            if (act) u[j] = *(const uint2*)(X16 + (long)s * F_IN + sl * 4);
        }
        #pragma unroll
        for (int j = 0; j < 8; ++j) {
            bool valid = (b + j) < n;
            float c = valid ? __int_as_float(e[j].y) : 0.0f;
            float2 f0 = __half22float2(*(__half2*)&u[j].x);
            float2 f1 = __half22float2(*(__half2*)&u[j].y);
            acc.x += c * f0.x; acc.y += c * f0.y; acc.z += c * f1.x; acc.w += c * f1.y;
        }
    }
    // write row [v][K1P]: lanes 0..27 real cols, lanes 28..31 zero the K pad
    if (sl < 32) {
        uint2 o = {0, 0};
        if (act) {
            __half2 h0 = __floats2half2_rn(acc.x, acc.y);
            __half2 h1 = __floats2half2_rn(acc.z, acc.w);
            o.x = *(unsigned*)&h0; o.y = *(unsigned*)&h1;
        }
        *(uint2*)(aX + (long)v * K1P + sl * 4) = o;
    }
}

// ---------------- fp16 MFMA GEMM: C = A[M,KP] @ Bt[N,KP]^T ----------------
template<int KP, int EPI>
__global__ __launch_bounds__(256) void k_gemm_f16(
        const ushort_t* __restrict__ A, const ushort_t* __restrict__ Bt,
        const float* __restrict__ bias,
        ushort_t* __restrict__ C, int M, int Nreal, int CW) {
    __shared__ ushort_t As[128][40];
    __shared__ ushort_t Bs[64][40];
    const int tid = threadIdx.x;
    const int row0 = blockIdx.y * 128;
    const int col0 = blockIdx.x * 64;
    const int w  = tid >> 6, l = tid & 63;
    const int wm = w >> 1, wn = w & 1;
    const int lm = l & 15, lq = l >> 4;

    f32x4 acc[4][2];
    #pragma unroll
    for (int i = 0; i < 4; ++i)
        #pragma unroll
        for (int j = 0; j < 2; ++j) acc[i][j] = (f32x4){0.f, 0.f, 0.f, 0.f};

    const int arow  = tid >> 2;
    const int akoff = (tid & 3) * 8;

    for (int k0 = 0; k0 < KP; k0 += 32) {
        *(int4*)&As[arow][akoff]      = *(const int4*)&A[(long)(row0 + arow) * KP + k0 + akoff];
        *(int4*)&As[arow + 64][akoff] = *(const int4*)&A[(long)(row0 + arow + 64) * KP + k0 + akoff];
        *(int4*)&Bs[arow][akoff]      = *(const int4*)&Bt[(long)(col0 + arow) * KP + k0 + akoff];
        __syncthreads();

        f16x8 af[4], bf[2];
        #pragma unroll
        for (int ms = 0; ms < 4; ++ms)
            af[ms] = *(const f16x8*)&As[wm * 64 + ms * 16 + lm][lq * 8];
        #pragma unroll
        for (int ns = 0; ns < 2; ++ns)
            bf[ns] = *(const f16x8*)&Bs[wn * 32 + ns * 16 + lm][lq * 8];
        #pragma unroll
        for (int ms = 0; ms < 4; ++ms)
            #pragma unroll
            for (int ns = 0; ns < 2; ++ns)
                acc[ms][ns] = __builtin_amdgcn_mfma_f32_16x16x32_f16(af[ms], bf[ns], acc[ms][ns], 0, 0, 0);
        __syncthreads();
    }

    #pragma unroll
    for (int ms = 0; ms < 4; ++ms) {
        int R = row0 + wm * 64 + ms * 16 + lq * 4;
        #pragma unroll
        for (int ns = 0; ns < 2; ++ns) {
            int col = col0 + wn * 32 + ns * 16 + lm;
            if (EPI == 1) {
                if (col < CW) {
                    float bb = (col < Nreal) ? bias[col] : 0.0f;
                    #pragma unroll
                    for (int i = 0; i < 4; ++i) {
                        int row = R + i;
                        if (row < M) {
                            float r = (col < Nreal) ? fmaxf(acc[ms][ns][i] + bb, 0.0f) : 0.0f;
                            C[(long)row * CW + col] = f16_bits(r);
                        }
                    }
                }
            } else {
                if (col < Nreal) {
                    #pragma unroll
                    for (int i = 0; i < 4; ++i) {
                        int row = R + i;
                        if (row < M) C[(long)row * Nreal + col] = f16_bits(acc[ms][ns][i]);
                    }
                }
            }
        }
    }
}

// ---------------- agg layer 2: 2 nodes/wave, depth-8, + bias + relu -> fp16 ----------------
// lanes 0-20: node 2w, lanes 32-52: node 2w+1; uint4 (8 fp16) per lane
__global__ __launch_bounds__(256) void k_agg2(const ushort_t* __restrict__ T16,
                                              const int* __restrict__ off,
                                              const int2* __restrict__ csr,
                                              const float* __restrict__ dinv,
                                              const float* __restrict__ b2,
                                              ushort_t* __restrict__ out2) {
    int w = (blockIdx.x * 256 + threadIdx.x) >> 6;
    int lane = threadIdx.x & 63;
    if (w >= N_NODES / 2) return;
    const int g = lane >> 5, sl = lane & 31;
    const int v = 2 * w + g;
    const bool act = sl < 21;                     // 21 lanes x 8 feats = 168
    int o0A = off[2 * w], oM = off[2 * w + 1], o1B = off[2 * w + 2];
    int o0 = g ? oM : o0A;
    int n  = g ? (o1B - oM) : (oM - o0A);
    int nmax = max(oM - o0A, o1B - oM);
    float di = dinv[v];
    float4 a0 = {0, 0, 0, 0}, a1 = {0, 0, 0, 0};
    if (act) {
        uint4 u = *(const uint4*)(T16 + (long)v * F2 + sl * 8);
        float2 f0 = __half22float2(*(__half2*)&u.x);
        float2 f1 = __half22float2(*(__half2*)&u.y);
        float2 f2 = __half22float2(*(__half2*)&u.z);
        float2 f3 = __half22float2(*(__half2*)&u.w);
        float s2 = di * di;
        a0.x = f0.x * s2; a0.y = f0.y * s2; a0.z = f1.x * s2; a0.w = f1.y * s2;
        a1.x = f2.x * s2; a1.y = f2.y * s2; a1.z = f3.x * s2; a1.w = f3.y * s2;
    }
    int nm1 = max(n - 1, 0);
    for (int b = 0; b < nmax; b += 8) {
        int2 e[8];
        #pragma unroll
        for (int j = 0; j < 8; ++j) {
            int cidx = min(o0 + min(b + j, nm1), N_EDGES - 1);
            e[j] = csr[cidx];
        }
        uint4 u[8];
        #pragma unroll
        for (int j = 0; j < 8; ++j) {
            bool valid = (b + j) < n;
            int s = valid ? e[j].x : v;
            if (act) u[j] = *(const uint4*)(T16 + (long)s * F2 + sl * 8);
        }
        #pragma unroll
        for (int j = 0; j < 8; ++j) {
            bool valid = (b + j) < n;
            float c = valid ? __int_as_float(e[j].y) : 0.0f;
            float2 f0 = __half22float2(*(__half2*)&u[j].x);
            float2 f1 = __half22float2(*(__half2*)&u[j].y);
            float2 f2 = __half22float2(*(__half2*)&u[j].z);
            float2 f3 = __half22float2(*(__half2*)&u[j].w);
            a0.x += c * f0.x; a0.y += c * f0.y; a0.z += c * f1.x; a0.w += c * f1.y;
            a1.x += c * f2.x; a1.y += c * f2.y; a1.z += c * f3.x; a1.w += c * f3.y;
        }
    }
    if (act) {
        float4 bb0 = ((const float4*)b2)[sl * 2];
        float4 bb1 = ((const float4*)b2)[sl * 2 + 1];
        __half2 h0 = __floats2half2_rn(fmaxf(a0.x + bb0.x, 0.0f), fmaxf(a0.y + bb0.y, 0.0f));
        __half2 h1 = __floats2half2_rn(fmaxf(a0.z + bb0.z, 0.0f), fmaxf(a0.w + bb0.w, 0.0f));
        __half2 h2 = __floats2half2_rn(fmaxf(a1.x + bb1.x, 0.0f), fmaxf(a1.y + bb1.y, 0.0f));
        __half2 h3 = __floats2half2_rn(fmaxf(a1.z + bb1.z, 0.0f), fmaxf(a1.w + bb1.w, 0.0f));
        uint4 o;
        o.x = *(unsigned*)&h0; o.y = *(unsigned*)&h1;
        o.z = *(unsigned*)&h2; o.w = *(unsigned*)&h3;
        *(uint4*)(out2 + (long)v * F2 + sl * 8) = o;
    }
}

// ---------------- fused per-graph max pool + MLP head ----------------
__global__ __launch_bounds__(256) void k_pool_head(const ushort_t* __restrict__ out2,
        const int* __restrict__ r0, const int* __restrict__ r1,
        const float* __restrict__ Wg, const float* __restrict__ bg,
        const float* __restrict__ Wf, const float* __restrict__ bf,
        const float* __restrict__ Wo, const float* __restrict__ bo,
        float* __restrict__ out) {
    __shared__ float4 sm[4][F2 / 4];
    __shared__ float s0[F2];
    __shared__ float s1[84];
    __shared__ float s2[42];
    int gi = blockIdx.x;
    int slot = threadIdx.x >> 6, lane = threadIdx.x & 63;
    int a = r0[gi], b = r1[gi];
    if (lane < F2 / 4) {
        float4 mx = {0, 0, 0, 0};    // post-relu values >= 0
        for (int v = a + slot; v < b; v += 4) {
            uint2 u = ((const uint2*)(out2 + (long)v * F2))[lane];
            float2 f0 = __half22float2(*(__half2*)&u.x);
            float2 f1 = __half22float2(*(__half2*)&u.y);
            mx.x = fmaxf(mx.x, f0.x); mx.y = fmaxf(mx.y, f0.y);
            mx.z = fmaxf(mx.z, f1.x); mx.w = fmaxf(mx.w, f1.y);
        }
        sm[slot][lane] = mx;
    }
    __syncthreads();
    if (slot == 0 && lane < F2 / 4) {
        float4 m0 = sm[0][lane], m1 = sm[1][lane], m2 = sm[2][lane], m3 = sm[3][lane];
        float4 r;
        r.x = fmaxf(fmaxf(m0.x, m1.x), fmaxf(m2.x, m3.x));
        r.y = fmaxf(fmaxf(m0.y, m1.y), fmaxf(m2.y, m3.y));
        r.z = fmaxf(fmaxf(m0.z, m1.z), fmaxf(m2.z, m3.z));
        r.w = fmaxf(fmaxf(m0.w, m1.w), fmaxf(m2.w, m3.w));
        ((float4*)s0)[lane] = r;
    }
    __syncthreads();
    int t = threadIdx.x;
    if (t < 84) {
        float acc = bg[t];
        #pragma unroll 4
        for (int k = 0; k < F2; ++k) acc += s0[k] * Wg[k * 84 + t];
        s1[t] = fmaxf(acc, 0.0f);
    }
    __syncthreads();
    if (t < 42) {
        float acc = bf[t];
        #pragma unroll 4
        for (int k = 0; k < 84; ++k) acc += s1[k] * Wf[k * 42 + t];
        s2[t] = fmaxf(acc, 0.0f);
    }
    __syncthreads();
    if (t == 0) {
        float acc = bo[0];
        for (int k = 0; k < 42; ++k) acc += s2[k] * Wo[k];
        out[gi] = acc;
    }
}

extern "C" void kernel_launch(void* const* d_in, const int* in_sizes, int n_in,
                              void* d_out, int out_size, void* d_ws, size_t ws_size,
                              hipStream_t stream) {
    const float* x   = (const float*)d_in[0];
    const int*   ei  = (const int*)d_in[1];
    const int*   bat = (const int*)d_in[2];
    const float* W1  = (const float*)d_in[3];
    const float* b1  = (const float*)d_in[4];
    const float* W2  = (const float*)d_in[5];
    const float* b2  = (const float*)d_in[6];
    const float* Wg  = (const float*)d_in[7];
    const float* bg  = (const float*)d_in[8];
    const float* Wf  = (const float*)d_in[9];
    const float* bf  = (const float*)d_in[10];
    const float* Wo  = (const float*)d_in[11];
    const float* bo  = (const float*)d_in[12];
    float* out = (float*)d_out;

    // ---- workspace carve-up (16B-aligned chunks; dcount+cur adjacent) ----
    char* p = (char*)d_ws;
    float* dinv     = (float*)p; p += 50048 * 4;
    int*   dcount   = (int*)p;   p += 50048 * 4;
    int*   cur      = (int*)p;   p += 50048 * 4;
    int*   off      = (int*)p;   p += 50064 * 4;
    int*   partials = (int*)p;   p += 64 * 4;
    int*   rng0     = (int*)p;   p += 256 * 4;
    int*   rng1     = (int*)p;   p += 256 * 4;
    int2*  csr      = (int2*)p;  p += (long)N_EDGES * 8;
    ushort_t* x16   = (ushort_t*)p; p += (long)N_NODES * F_IN * 2;
    ushort_t* aX    = (ushort_t*)p; p += (long)MPAD * K1P * 2;
    ushort_t* w1t   = (ushort_t*)p; p += (long)384 * K1P * 2;
    ushort_t* w2t   = (ushort_t*)p; p += (long)192 * K2P * 2;
    ushort_t* h1    = (ushort_t*)p; p += (long)MPAD * K2P * 2;
    ushort_t* t16   = (ushort_t*)p; p += (long)N_NODES * F2 * 2;
    ushort_t* o16   = (ushort_t*)p; p += (long)N_NODES * F2 * 2;

    const int* src = ei;
    const int* dst = ei + N_EDGES;
    const int B = 256;

    // ---- preproc ----
    k_zero_int<<<(2 * 50048 + B - 1) / B, B, 0, stream>>>(dcount, 2 * 50048);
    k_count_deg<<<(N_EDGES / 2 + B - 1) / B, B, 0, stream>>>(dst, dcount, N_EDGES / 2);
    k_prep<<<PREP_BLOCKS, B, 0, stream>>>(x, W1, W2, bat, x16, w1t, w2t, rng0, rng1);
    k_scan1<<<SCAN_BLOCKS, SCAN_CHUNK, 0, stream>>>(dcount, off, partials, dinv, N_NODES);
    k_scan3<<<SCAN_BLOCKS, SCAN_CHUNK, 0, stream>>>(off, partials, N_NODES);
    k_scatter<<<(N_EDGES + B - 1) / B, B, 0, stream>>>(src, dst, off, cur, dinv, csr, N_EDGES);

    // ---- layer 1 ----
    k_agg1<<<(N_NODES / 2 * 64) / 256, 256, 0, stream>>>(x16, off, csr, dinv, aX);
    dim3 gg1(6, MPAD / 128);
    k_gemm_f16<K1P, 1><<<gg1, 256, 0, stream>>>(aX, w1t, b1, h1, N_NODES, F1, K2P);

    // ---- layer 2 ----
    dim3 gg2(3, MPAD / 128);
    k_gemm_f16<K2P, 2><<<gg2, 256, 0, stream>>>(h1, w2t, nullptr, t16, N_NODES, F2, 0);
    k_agg2<<<(N_NODES / 2 * 64) / 256, 256, 0, stream>>>(t16, off, csr, dinv, b2, o16);

    // ---- pool + head fused ----
    k_pool_head<<<NGRAPH, 256, 0, stream>>>(o16, rng0, rng1, Wg, bg, Wf, bf, Wo, bo, out);
}

// Round 9
// 290.555 us; speedup vs baseline: 1.4814x; 1.0306x over previous
//
#include <hip/hip_runtime.h>
#include <hip/hip_fp16.h>

#define N_NODES 50000
#define MPAD    50048            // 782 * 64
#define N_EDGES 500000
#define F_IN    112
#define K1P     128              // F_IN padded to 32-multiple
#define F1      336
#define K2P     352              // F1 padded to 32-multiple
#define F2      168
#define NGRAPH  256
#define SCAN_CHUNK 1024
#define SCAN_BLOCKS ((N_NODES + SCAN_CHUNK - 1) / SCAN_CHUNK)   // 49

typedef __attribute__((ext_vector_type(8))) _Float16 f16x8;
typedef __attribute__((ext_vector_type(4))) float f32x4;
typedef unsigned short ushort_t;

__device__ __forceinline__ ushort_t f16_bits(float x) {
    __half h = __float2half_rn(x);
    return *(ushort_t*)&h;
}

// ---------------- small utility kernels ----------------
__global__ void k_zero_int(int* p, int n) {
    int i = blockIdx.x * blockDim.x + threadIdx.x;
    if (i < n) p[i] = 0;
}

// ---------------- fused prep: cvtX | count_deg | cvtW1 | cvtW2 | ranges ----------------
#define CVX_BLOCKS  ((N_NODES * (F_IN / 4) + 255) / 256)   // 5469
#define CNT_BLOCKS  ((N_EDGES / 2 + 255) / 256)            // 977
#define CVW1_BLOCKS ((384 * K1P + 255) / 256)              // 192
#define CVW2_BLOCKS ((192 * K2P + 255) / 256)              // 264
#define RNG_BLOCKS  ((N_NODES + 255) / 256)                // 196
#define PREP_BLOCKS (CVX_BLOCKS + CNT_BLOCKS + CVW1_BLOCKS + CVW2_BLOCKS + RNG_BLOCKS)

__global__ __launch_bounds__(256) void k_prep(const float* __restrict__ x,
                                              const int* __restrict__ dst,
                                              const float* __restrict__ W1,
                                              const float* __restrict__ W2,
                                              const int* __restrict__ batch,
                                              ushort_t* __restrict__ x16,
                                              int* __restrict__ dcount,
                                              ushort_t* __restrict__ w1t,
                                              ushort_t* __restrict__ w2t,
                                              int* __restrict__ r0, int* __restrict__ r1) {
    int bid = blockIdx.x;
    int t = threadIdx.x;
    if (bid < CVX_BLOCKS) {                       // X fp32 -> fp16, 4/thread
        int i = bid * 256 + t;
        if (i < N_NODES * (F_IN / 4)) {
            float4 v = ((const float4*)x)[i];
            __half2 h0 = __floats2half2_rn(v.x, v.y);
            __half2 h1 = __floats2half2_rn(v.z, v.w);
            uint2 u; u.x = *(unsigned*)&h0; u.y = *(unsigned*)&h1;
            ((uint2*)x16)[i] = u;
        }
        return;
    }
    bid -= CVX_BLOCKS;
    if (bid < CNT_BLOCKS) {                       // degree count, 2 edges/thread
        int i = bid * 256 + t;
        if (i < N_EDGES / 2) {
            int2 d = ((const int2*)dst)[i];
            atomicAdd(&dcount[d.x], 1);
            atomicAdd(&dcount[d.y], 1);
        }
        return;
    }
    bid -= CNT_BLOCKS;
    if (bid < CVW1_BLOCKS) {                      // W1[K,N] -> w1t[n][k] fp16
        int idx = bid * 256 + t;
        if (idx < 384 * K1P) {
            int n = idx / K1P, k = idx % K1P;
            float v = (n < F1 && k < F_IN) ? W1[k * F1 + n] : 0.0f;
            w1t[idx] = f16_bits(v);
        }
        return;
    }
    bid -= CVW1_BLOCKS;
    if (bid < CVW2_BLOCKS) {                      // W2[K,N] -> w2t[n][k] fp16
        int idx = bid * 256 + t;
        if (idx < 192 * K2P) {
            int n = idx / K2P, k = idx % K2P;
            float v = (n < F2 && k < F1) ? W2[k * F2 + n] : 0.0f;
            w2t[idx] = f16_bits(v);
        }
        return;
    }
    bid -= CVW2_BLOCKS;
    {                                             // per-graph ranges (batch sorted)
        int v = bid * 256 + t;
        if (v >= N_NODES) return;
        int b = batch[v];
        if (v == 0 || batch[v - 1] != b) r0[b] = v;
        if (v == N_NODES - 1 || batch[v + 1] != b) r1[b] = v + 1;
    }
}

// ---------------- scan pass 1 (dinv fused) ----------------
__global__ __launch_bounds__(SCAN_CHUNK) void k_scan1(const int* __restrict__ dcount,
                                                      int* __restrict__ off,
                                                      int* __restrict__ partials,
                                                      float* __restrict__ dinv, int n) {
    __shared__ int s[SCAN_CHUNK];
    int t = threadIdx.x;
    int i = blockIdx.x * SCAN_CHUNK + t;
    int val = (i < n) ? dcount[i] : 0;
    s[t] = val;
    __syncthreads();
    for (int d = 1; d < SCAN_CHUNK; d <<= 1) {
        int x = (t >= d) ? s[t - d] : 0;
        __syncthreads();
        s[t] += x;
        __syncthreads();
    }
    if (i < n) {
        off[i] = s[t] - val;
        dinv[i] = rsqrtf((float)val + 1.0f);      // +1 self-loop
    }
    if (t == SCAN_CHUNK - 1) partials[blockIdx.x] = s[t];
}
// scan pass 2+3 merged: each block redundantly prefixes the 49 partials
__global__ __launch_bounds__(SCAN_CHUNK) void k_scan3(int* __restrict__ off,
                                                      const int* __restrict__ partials, int n) {
    __shared__ int tmp[SCAN_BLOCKS];
    __shared__ int pref[SCAN_BLOCKS];
    int t = threadIdx.x;
    if (t < SCAN_BLOCKS) tmp[t] = partials[t];
    __syncthreads();
    if (t == 0) {
        int run = 0;
        for (int j = 0; j < SCAN_BLOCKS; ++j) { pref[j] = run; run += tmp[j]; }
    }
    __syncthreads();
    int i = blockIdx.x * SCAN_CHUNK + t;
    if (i < n) off[i] += pref[blockIdx.x];
    if (i == n) off[i] = N_EDGES;
}

// ---------------- scatter edges into dst-sorted CSR, 2 edges/thread ----------------
__global__ void k_scatter(const int* __restrict__ src, const int* __restrict__ dst,
                          const int* __restrict__ off, int* __restrict__ cur,
                          const float* __restrict__ dinv,
                          int2* __restrict__ csr, int e2) {
    int i = blockIdx.x * blockDim.x + threadIdx.x;
    if (i >= e2) return;
    int2 s2 = ((const int2*)src)[i];
    int2 d2 = ((const int2*)dst)[i];
    {
        int pos = atomicAdd(&cur[d2.x], 1);
        int2 rec; rec.x = s2.x; rec.y = __float_as_int(dinv[s2.x] * dinv[d2.x]);
        csr[off[d2.x] + pos] = rec;
    }
    {
        int pos = atomicAdd(&cur[d2.y], 1);
        int2 rec; rec.x = s2.y; rec.y = __float_as_int(dinv[s2.y] * dinv[d2.y]);
        csr[off[d2.y] + pos] = rec;
    }
}

// ---------------- agg layer 1: 2 nodes/wave (half-wave each), depth-8 ----------------
__global__ __launch_bounds__(256) void k_agg1(const ushort_t* __restrict__ X16,
                                              const int* __restrict__ off,
                                              const int2* __restrict__ csr,
                                              const float* __restrict__ dinv,
                                              ushort_t* __restrict__ aX) {
    int w = (blockIdx.x * 256 + threadIdx.x) >> 6;
    int lane = threadIdx.x & 63;
    if (w >= N_NODES / 2) return;
    const int g = lane >> 5, sl = lane & 31;
    const int v = 2 * w + g;
    const bool act = sl < 28;                     // 28 lanes x 4 feats = 112
    int o0A = off[2 * w], oM = off[2 * w + 1], o1B = off[2 * w + 2];
    int o0 = g ? oM : o0A;
    int n  = g ? (o1B - oM) : (oM - o0A);
    int nmax = max(oM - o0A, o1B - oM);
    float di = dinv[v];
    float4 acc = {0, 0, 0, 0};
    if (act) {
        uint2 u = *(const uint2*)(X16 + (long)v * F_IN + sl * 4);
        float2 f0 = __half22float2(*(__half2*)&u.x);
        float2 f1 = __half22float2(*(__half2*)&u.y);
        float s2 = di * di;
        acc.x = f0.x * s2; acc.y = f0.y * s2; acc.z = f1.x * s2; acc.w = f1.y * s2;
    }
    int nm1 = max(n - 1, 0);
    for (int b = 0; b < nmax; b += 8) {
        int2 e[8];
        #pragma unroll
        for (int j = 0; j < 8; ++j) {
            int cidx = min(o0 + min(b + j, nm1), N_EDGES - 1);
            e[j] = csr[cidx];
        }
        uint2 u[8];
        #pragma unroll
        for (int j = 0; j < 8; ++j) {
            bool valid = (b + j) < n;
            int s = valid ? e[j].x : v;
            if (act) u[j] = *(const uint2*)(X16 + (long)s * F_IN + sl * 4);
        }
        #pragma unroll
        for (int j = 0; j < 8; ++j) {
            bool valid = (b + j) < n;
            float c = valid ? __int_as_float(e[j].y) : 0.0f;
            float2 f0 = __half22float2(*(__half2*)&u[j].x);
            float2 f1 = __half22float2(*(__half2*)&u[j].y);
            acc.x += c * f0.x; acc.y += c * f0.y; acc.z += c * f1.x; acc.w += c * f1.y;
        }
    }
    if (sl < 32) {
        uint2 o = {0, 0};
        if (act) {
            __half2 h0 = __floats2half2_rn(acc.x, acc.y);
            __half2 h1 = __floats2half2_rn(acc.z, acc.w);
            o.x = *(unsigned*)&h0; o.y = *(unsigned*)&h1;
        }
        *(uint2*)(aX + (long)v * K1P + sl * 4) = o;
    }
}

// ---------------- fp16 MFMA GEMM, wide-N tiles: C = A[M,KP] @ Bt[N,KP]^T ----------------
// M-tile 64, N-tile NT (128 or 192). 256 threads = 4 waves (2x2).
// Wave tile 32 x NT/2 ; per lane: 2 x (NT/32) f32x4 accumulators.
// A-row-block is streamed ONCE per grid column (NT wide) -> minimal A re-reads.
template<int NT, int KP, int EPI>
__global__ __launch_bounds__(256) void k_gemm_f16(
        const ushort_t* __restrict__ A, const ushort_t* __restrict__ Bt,
        const float* __restrict__ bias,
        ushort_t* __restrict__ C, int M, int Nreal, int CW) {
    constexpr int NS = NT / 32;        // ns tiles per wave
    __shared__ ushort_t As[64][40];    // k-major, 80 B rows
    __shared__ ushort_t Bs[NT][40];
    const int tid = threadIdx.x;
    const int row0 = blockIdx.y * 64;
    const int col0 = blockIdx.x * NT;
    const int w  = tid >> 6, l = tid & 63;
    const int wm = w >> 1, wn = w & 1;
    const int lm = l & 15, lq = l >> 4;

    f32x4 acc[2][NS];
    #pragma unroll
    for (int i = 0; i < 2; ++i)
        #pragma unroll
        for (int j = 0; j < NS; ++j) acc[i][j] = (f32x4){0.f, 0.f, 0.f, 0.f};

    const int arow  = tid >> 2;        // 0..63
    const int akoff = (tid & 3) * 8;   // 0,8,16,24

    for (int k0 = 0; k0 < KP; k0 += 32) {
        *(int4*)&As[arow][akoff] = *(const int4*)&A[(long)(row0 + arow) * KP + k0 + akoff];
        #pragma unroll
        for (int c = 0; c < NT / 64; ++c)
            *(int4*)&Bs[c * 64 + arow][akoff] =
                *(const int4*)&Bt[(long)(col0 + c * 64 + arow) * KP + k0 + akoff];
        __syncthreads();

        f16x8 af[2], bf[NS];
        #pragma unroll
        for (int ms = 0; ms < 2; ++ms)
            af[ms] = *(const f16x8*)&As[wm * 32 + ms * 16 + lm][lq * 8];
        #pragma unroll
        for (int ns = 0; ns < NS; ++ns)
            bf[ns] = *(const f16x8*)&Bs[wn * (NT / 2) + ns * 16 + lm][lq * 8];
        #pragma unroll
        for (int ms = 0; ms < 2; ++ms)
            #pragma unroll
            for (int ns = 0; ns < NS; ++ns)
                acc[ms][ns] = __builtin_amdgcn_mfma_f32_16x16x32_f16(af[ms], bf[ns], acc[ms][ns], 0, 0, 0);
        __syncthreads();
    }

    // epilogue: C/D layout col=lane&15, row=(lane>>4)*4+i
    #pragma unroll
    for (int ms = 0; ms < 2; ++ms) {
        int R = row0 + wm * 32 + ms * 16 + lq * 4;
        #pragma unroll
        for (int ns = 0; ns < NS; ++ns) {
            int col = col0 + wn * (NT / 2) + ns * 16 + lm;
            if (EPI == 1) {
                if (col < CW) {
                    float bb = (col < Nreal) ? bias[col] : 0.0f;
                    #pragma unroll
                    for (int i = 0; i < 4; ++i) {
                        int row = R + i;
                        if (row < M) {
                            float r = (col < Nreal) ? fmaxf(acc[ms][ns][i] + bb, 0.0f) : 0.0f;
                            C[(long)row * CW + col] = f16_bits(r);
                        }
                    }
                }
            } else {
                if (col < Nreal) {
                    #pragma unroll
                    for (int i = 0; i < 4; ++i) {
                        int row = R + i;
                        if (row < M) C[(long)row * Nreal + col] = f16_bits(acc[ms][ns][i]);
                    }
                }
            }
        }
    }
}

// ---------------- agg layer 2: 2 nodes/wave, depth-8, + bias + relu -> fp16 ----------------
__global__ __launch_bounds__(256) void k_agg2(const ushort_t* __restrict__ T16,
                                              const int* __restrict__ off,
                                              const int2* __restrict__ csr,
                                              const float* __restrict__ dinv,
                                              const float* __restrict__ b2,
                                              ushort_t* __restrict__ out2) {
    int w = (blockIdx.x * 256 + threadIdx.x) >> 6;
    int lane = threadIdx.x & 63;
    if (w >= N_NODES / 2) return;
    const int g = lane >> 5, sl = lane & 31;
    const int v = 2 * w + g;
    const bool act = sl < 21;                     // 21 lanes x 8 feats = 168
    int o0A = off[2 * w], oM = off[2 * w + 1], o1B = off[2 * w + 2];
    int o0 = g ? oM : o0A;
    int n  = g ? (o1B - oM) : (oM - o0A);
    int nmax = max(oM - o0A, o1B - oM);
    float di = dinv[v];
    float4 a0 = {0, 0, 0, 0}, a1 = {0, 0, 0, 0};
    if (act) {
        uint4 u = *(const uint4*)(T16 + (long)v * F2 + sl * 8);
        float2 f0 = __half22float2(*(__half2*)&u.x);
        float2 f1 = __half22float2(*(__half2*)&u.y);
        float2 f2 = __half22float2(*(__half2*)&u.z);
        float2 f3 = __half22float2(*(__half2*)&u.w);
        float s2 = di * di;
        a0.x = f0.x * s2; a0.y = f0.y * s2; a0.z = f1.x * s2; a0.w = f1.y * s2;
        a1.x = f2.x * s2; a1.y = f2.y * s2; a1.z = f3.x * s2; a1.w = f3.y * s2;
    }
    int nm1 = max(n - 1, 0);
    for (int b = 0; b < nmax; b += 8) {
        int2 e[8];
        #pragma unroll
        for (int j = 0; j < 8; ++j) {
            int cidx = min(o0 + min(b + j, nm1), N_EDGES - 1);
            e[j] = csr[cidx];
        }
        uint4 u[8];
        #pragma unroll
        for (int j = 0; j < 8; ++j) {
            bool valid = (b + j) < n;
            int s = valid ? e[j].x : v;
            if (act) u[j] = *(const uint4*)(T16 + (long)s * F2 + sl * 8);
        }
        #pragma unroll
        for (int j = 0; j < 8; ++j) {
            bool valid = (b + j) < n;
            float c = valid ? __int_as_float(e[j].y) : 0.0f;
            float2 f0 = __half22float2(*(__half2*)&u[j].x);
            float2 f1 = __half22float2(*(__half2*)&u[j].y);
            float2 f2 = __half22float2(*(__half2*)&u[j].z);
            float2 f3 = __half22float2(*(__half2*)&u[j].w);
            a0.x += c * f0.x; a0.y += c * f0.y; a0.z += c * f1.x; a0.w += c * f1.y;
            a1.x += c * f2.x; a1.y += c * f2.y; a1.z += c * f3.x; a1.w += c * f3.y;
        }
    }
    if (act) {
        float4 bb0 = ((const float4*)b2)[sl * 2];
        float4 bb1 = ((const float4*)b2)[sl * 2 + 1];
        __half2 h0 = __floats2half2_rn(fmaxf(a0.x + bb0.x, 0.0f), fmaxf(a0.y + bb0.y, 0.0f));
        __half2 h1 = __floats2half2_rn(fmaxf(a0.z + bb0.z, 0.0f), fmaxf(a0.w + bb0.w, 0.0f));
        __half2 h2 = __floats2half2_rn(fmaxf(a1.x + bb1.x, 0.0f), fmaxf(a1.y + bb1.y, 0.0f));
        __half2 h3 = __floats2half2_rn(fmaxf(a1.z + bb1.z, 0.0f), fmaxf(a1.w + bb1.w, 0.0f));
        uint4 o;
        o.x = *(unsigned*)&h0; o.y = *(unsigned*)&h1;
        o.z = *(unsigned*)&h2; o.w = *(unsigned*)&h3;
        *(uint4*)(out2 + (long)v * F2 + sl * 8) = o;
    }
}

// ---------------- fused per-graph max pool + MLP head ----------------
__global__ __launch_bounds__(256) void k_pool_head(const ushort_t* __restrict__ out2,
        const int* __restrict__ r0, const int* __restrict__ r1,
        const float* __restrict__ Wg, const float* __restrict__ bg,
        const float* __restrict__ Wf, const float* __restrict__ bf,
        const float* __restrict__ Wo, const float* __restrict__ bo,
        float* __restrict__ out) {
    __shared__ float4 sm[4][F2 / 4];
    __shared__ float s0[F2];
    __shared__ float s1[84];
    __shared__ float s2[42];
    int gi = blockIdx.x;
    int slot = threadIdx.x >> 6, lane = threadIdx.x & 63;
    int a = r0[gi], b = r1[gi];
    if (lane < F2 / 4) {
        float4 mx = {0, 0, 0, 0};
        for (int v = a + slot; v < b; v += 4) {
            uint2 u = ((const uint2*)(out2 + (long)v * F2))[lane];
            float2 f0 = __half22float2(*(__half2*)&u.x);
            float2 f1 = __half22float2(*(__half2*)&u.y);
            mx.x = fmaxf(mx.x, f0.x); mx.y = fmaxf(mx.y, f0.y);
            mx.z = fmaxf(mx.z, f1.x); mx.w = fmaxf(mx.w, f1.y);
        }
        sm[slot][lane] = mx;
    }
    __syncthreads();
    if (slot == 0 && lane < F2 / 4) {
        float4 m0 = sm[0][lane], m1 = sm[1][lane], m2 = sm[2][lane], m3 = sm[3][lane];
        float4 r;
        r.x = fmaxf(fmaxf(m0.x, m1.x), fmaxf(m2.x, m3.x));
        r.y = fmaxf(fmaxf(m0.y, m1.y), fmaxf(m2.y, m3.y));
        r.z = fmaxf(fmaxf(m0.z, m1.z), fmaxf(m2.z, m3.z));
        r.w = fmaxf(fmaxf(m0.w, m1.w), fmaxf(m2.w, m3.w));
        ((float4*)s0)[lane] = r;
    }
    __syncthreads();
    int t = threadIdx.x;
    if (t < 84) {
        float acc = bg[t];
        #pragma unroll 4
        for (int k = 0; k < F2; ++k) acc += s0[k] * Wg[k * 84 + t];
        s1[t] = fmaxf(acc, 0.0f);
    }
    __syncthreads();
    if (t < 42) {
        float acc = bf[t];
        #pragma unroll 4
        for (int k = 0; k < 84; ++k) acc += s1[k] * Wf[k * 42 + t];
        s2[t] = fmaxf(acc, 0.0f);
    }
    __syncthreads();
    if (t == 0) {
        float acc = bo[0];
        for (int k = 0; k < 42; ++k) acc += s2[k] * Wo[k];
        out[gi] = acc;
    }
}

extern "C" void kernel_launch(void* const* d_in, const int* in_sizes, int n_in,
                              void* d_out, int out_size, void* d_ws, size_t ws_size,
                              hipStream_t stream) {
    const float* x   = (const float*)d_in[0];
    const int*   ei  = (const int*)d_in[1];
    const int*   bat = (const int*)d_in[2];
    const float* W1  = (const float*)d_in[3];
    const float* b1  = (const float*)d_in[4];
    const float* W2  = (const float*)d_in[5];
    const float* b2  = (const float*)d_in[6];
    const float* Wg  = (const float*)d_in[7];
    const float* bg  = (const float*)d_in[8];
    const float* Wf  = (const float*)d_in[9];
    const float* bf  = (const float*)d_in[10];
    const float* Wo  = (const float*)d_in[11];
    const float* bo  = (const float*)d_in[12];
    float* out = (float*)d_out;

    // ---- workspace carve-up (16B-aligned chunks; dcount+cur adjacent) ----
    char* p = (char*)d_ws;
    float* dinv     = (float*)p; p += 50048 * 4;
    int*   dcount   = (int*)p;   p += 50048 * 4;
    int*   cur      = (int*)p;   p += 50048 * 4;
    int*   off      = (int*)p;   p += 50064 * 4;
    int*   partials = (int*)p;   p += 64 * 4;
    int*   rng0     = (int*)p;   p += 256 * 4;
    int*   rng1     = (int*)p;   p += 256 * 4;
    int2*  csr      = (int2*)p;  p += (long)N_EDGES * 8;
    ushort_t* x16   = (ushort_t*)p; p += (long)N_NODES * F_IN * 2;
    ushort_t* aX    = (ushort_t*)p; p += (long)MPAD * K1P * 2;
    ushort_t* w1t   = (ushort_t*)p; p += (long)384 * K1P * 2;
    ushort_t* w2t   = (ushort_t*)p; p += (long)192 * K2P * 2;
    ushort_t* h1    = (ushort_t*)p; p += (long)MPAD * K2P * 2;
    ushort_t* t16   = (ushort_t*)p; p += (long)N_NODES * F2 * 2;
    ushort_t* o16   = (ushort_t*)p; p += (long)N_NODES * F2 * 2;

    const int* src = ei;
    const int* dst = ei + N_EDGES;
    const int B = 256;

    // ---- preproc ----
    k_zero_int<<<(2 * 50048 + B - 1) / B, B, 0, stream>>>(dcount, 2 * 50048);
    k_prep<<<PREP_BLOCKS, B, 0, stream>>>(x, dst, W1, W2, bat, x16, dcount, w1t, w2t, rng0, rng1);
    k_scan1<<<SCAN_BLOCKS, SCAN_CHUNK, 0, stream>>>(dcount, off, partials, dinv, N_NODES);
    k_scan3<<<SCAN_BLOCKS, SCAN_CHUNK, 0, stream>>>(off, partials, N_NODES);
    k_scatter<<<(N_EDGES / 2 + B - 1) / B, B, 0, stream>>>(src, dst, off, cur, dinv, csr, N_EDGES / 2);

    // ---- layer 1 ----
    k_agg1<<<(N_NODES / 2 * 64) / 256, 256, 0, stream>>>(x16, off, csr, dinv, aX);
    dim3 gg1(3, MPAD / 64);    // 384/128 cols x 782 rows
    k_gemm_f16<128, K1P, 1><<<gg1, 256, 0, stream>>>(aX, w1t, b1, h1, N_NODES, F1, K2P);

    // ---- layer 2 ----
    dim3 gg2(1, MPAD / 64);    // 192-wide single col block x 782 rows
    k_gemm_f16<192, K2P, 2><<<gg2, 256, 0, stream>>>(h1, w2t, nullptr, t16, N_NODES, F2, 0);
    k_agg2<<<(N_NODES / 2 * 64) / 256, 256, 0, stream>>>(t16, off, csr, dinv, b2, o16);

    // ---- pool + head fused ----
    k_pool_head<<<NGRAPH, 256, 0, stream>>>(o16, rng0, rng1, Wg, bg, Wf, bf, Wo, bo, out);
}

// Round 10
// 284.460 us; speedup vs baseline: 1.5131x; 1.0214x over previous
//
#include <hip/hip_runtime.h>
#include <hip/hip_fp16.h>

#define N_NODES 50000
#define MPAD    50048            // 782 * 64
#define N_EDGES 500000
#define F_IN    112
#define K1P     128              // F_IN padded (halves per x16/aX row)
#define F1      336
#define K2P     352              // F1 padded to 32-multiple
#define F2      168
#define T2W     192              // T2 row width (halves), padded
#define NGRAPH  256
#define SCAN_CHUNK 1024
#define SCAN_BLOCKS ((N_NODES + SCAN_CHUNK - 1) / SCAN_CHUNK)   // 49

typedef __attribute__((ext_vector_type(8))) _Float16 f16x8;
typedef __attribute__((ext_vector_type(4))) float f32x4;
typedef unsigned short ushort_t;

__device__ __forceinline__ ushort_t f16_bits(float x) {
    __half h = __float2half_rn(x);
    return *(ushort_t*)&h;
}

// ---------------- small utility kernels ----------------
__global__ void k_zero_int(int* p, int n) {
    int i = blockIdx.x * blockDim.x + threadIdx.x;
    if (i < n) p[i] = 0;
}

// ---------------- fused prep: cvtX(pad128) | count_deg | cvtW1 | cvtW2 | ranges ----------------
#define CVX_BLOCKS  ((N_NODES * 32) / 256)                 // 6250 (uint2 per thread)
#define CNT_BLOCKS  ((N_EDGES / 2 + 255) / 256)            // 977
#define CVW1_BLOCKS ((384 * K1P + 255) / 256)              // 192
#define CVW2_BLOCKS ((192 * K2P + 255) / 256)              // 264
#define RNG_BLOCKS  ((N_NODES + 255) / 256)                // 196
#define PREP_BLOCKS (CVX_BLOCKS + CNT_BLOCKS + CVW1_BLOCKS + CVW2_BLOCKS + RNG_BLOCKS)

__global__ __launch_bounds__(256) void k_prep(const float* __restrict__ x,
                                              const int* __restrict__ dst,
                                              const float* __restrict__ W1,
                                              const float* __restrict__ W2,
                                              const int* __restrict__ batch,
                                              ushort_t* __restrict__ x16,   // [N][128]
                                              int* __restrict__ dcount,
                                              ushort_t* __restrict__ w1t,   // [384][128]
                                              ushort_t* __restrict__ w2t,   // [192][352]
                                              int* __restrict__ r0, int* __restrict__ r1) {
    int bid = blockIdx.x;
    int t = threadIdx.x;
    if (bid < CVX_BLOCKS) {                       // X fp32 -> fp16, padded rows of 128 halves
        int i = bid * 256 + t;                    // uint2 (4 halves) index; i = v*32 + c
        int v = i >> 5, c = i & 31;
        uint2 u = {0, 0};
        if (c < 28) {
            float4 f = *(const float4*)&x[(long)v * F_IN + c * 4];
            __half2 h0 = __floats2half2_rn(f.x, f.y);
            __half2 h1 = __floats2half2_rn(f.z, f.w);
            u.x = *(unsigned*)&h0; u.y = *(unsigned*)&h1;
        }
        ((uint2*)x16)[i] = u;
        return;
    }
    bid -= CVX_BLOCKS;
    if (bid < CNT_BLOCKS) {                       // degree count, 2 edges/thread
        int i = bid * 256 + t;
        if (i < N_EDGES / 2) {
            int2 d = ((const int2*)dst)[i];
            atomicAdd(&dcount[d.x], 1);
            atomicAdd(&dcount[d.y], 1);
        }
        return;
    }
    bid -= CNT_BLOCKS;
    if (bid < CVW1_BLOCKS) {                      // W1[K,N] -> w1t[n][k]
        int idx = bid * 256 + t;
        if (idx < 384 * K1P) {
            int n = idx / K1P, k = idx % K1P;
            float v = (n < F1 && k < F_IN) ? W1[k * F1 + n] : 0.0f;
            w1t[idx] = f16_bits(v);
        }
        return;
    }
    bid -= CVW1_BLOCKS;
    if (bid < CVW2_BLOCKS) {                      // W2[K,N] -> w2t[n][k]
        int idx = bid * 256 + t;
        if (idx < 192 * K2P) {
            int n = idx / K2P, k = idx % K2P;
            float v = (n < F2 && k < F1) ? W2[k * F2 + n] : 0.0f;
            w2t[idx] = f16_bits(v);
        }
        return;
    }
    bid -= CVW2_BLOCKS;
    {                                             // per-graph ranges (batch sorted)
        int v = bid * 256 + t;
        if (v >= N_NODES) return;
        int b = batch[v];
        if (v == 0 || batch[v - 1] != b) r0[b] = v;
        if (v == N_NODES - 1 || batch[v + 1] != b) r1[b] = v + 1;
    }
}

// ---------------- scan pass 1 (dinv fused) ----------------
__global__ __launch_bounds__(SCAN_CHUNK) void k_scan1(const int* __restrict__ dcount,
                                                      int* __restrict__ off,
                                                      int* __restrict__ partials,
                                                      float* __restrict__ dinv, int n) {
    __shared__ int s[SCAN_CHUNK];
    int t = threadIdx.x;
    int i = blockIdx.x * SCAN_CHUNK + t;
    int val = (i < n) ? dcount[i] : 0;
    s[t] = val;
    __syncthreads();
    for (int d = 1; d < SCAN_CHUNK; d <<= 1) {
        int x = (t >= d) ? s[t - d] : 0;
        __syncthreads();
        s[t] += x;
        __syncthreads();
    }
    if (i < n) {
        off[i] = s[t] - val;
        dinv[i] = rsqrtf((float)val + 1.0f);      // +1 self-loop
    }
    if (t == SCAN_CHUNK - 1) partials[blockIdx.x] = s[t];
}
// scan pass 2+3 merged
__global__ __launch_bounds__(SCAN_CHUNK) void k_scan3(int* __restrict__ off,
                                                      const int* __restrict__ partials, int n) {
    __shared__ int tmp[SCAN_BLOCKS];
    __shared__ int pref[SCAN_BLOCKS];
    int t = threadIdx.x;
    if (t < SCAN_BLOCKS) tmp[t] = partials[t];
    __syncthreads();
    if (t == 0) {
        int run = 0;
        for (int j = 0; j < SCAN_BLOCKS; ++j) { pref[j] = run; run += tmp[j]; }
    }
    __syncthreads();
    int i = blockIdx.x * SCAN_CHUNK + t;
    if (i < n) off[i] += pref[blockIdx.x];
    if (i == n) off[i] = N_EDGES;
}

// ---------------- scatter edges into dst-sorted CSR, 2 edges/thread ----------------
__global__ void k_scatter(const int* __restrict__ src, const int* __restrict__ dst,
                          const int* __restrict__ off, int* __restrict__ cur,
                          const float* __restrict__ dinv,
                          int2* __restrict__ csr, int e2) {
    int i = blockIdx.x * blockDim.x + threadIdx.x;
    if (i >= e2) return;
    int2 s2 = ((const int2*)src)[i];
    int2 d2 = ((const int2*)dst)[i];
    {
        int pos = atomicAdd(&cur[d2.x], 1);
        int2 rec; rec.x = s2.x; rec.y = __float_as_int(dinv[s2.x] * dinv[d2.x]);
        csr[off[d2.x] + pos] = rec;
    }
    {
        int pos = atomicAdd(&cur[d2.y], 1);
        int2 rec; rec.x = s2.y; rec.y = __float_as_int(dinv[s2.y] * dinv[d2.y]);
        csr[off[d2.y] + pos] = rec;
    }
}

// ---------------- agg layer 1: 2 nodes/wave, depth-16, padded 256B rows ----------------
__global__ __launch_bounds__(256) void k_agg1(const ushort_t* __restrict__ X16,
                                              const int* __restrict__ off,
                                              const int2* __restrict__ csr,
                                              const float* __restrict__ dinv,
                                              ushort_t* __restrict__ aX) {
    int w = (blockIdx.x * 256 + threadIdx.x) >> 6;
    int lane = threadIdx.x & 63;
    if (w >= N_NODES / 2) return;
    const int g = lane >> 5, sl = lane & 31;
    const int v = 2 * w + g;
    int o0A = off[2 * w], oM = off[2 * w + 1], o1B = off[2 * w + 2];
    int o0 = g ? oM : o0A;
    int n  = g ? (o1B - oM) : (oM - o0A);
    int nmax = max(oM - o0A, o1B - oM);
    float di = dinv[v];
    float s2 = di * di;
    // all 32 lanes live: pad cols are zero in X16, so they compute zeros
    uint2 us = *(const uint2*)(X16 + (long)v * K1P + sl * 4);
    float2 sf0 = __half22float2(*(__half2*)&us.x);
    float2 sf1 = __half22float2(*(__half2*)&us.y);
    float4 acc = {sf0.x * s2, sf0.y * s2, sf1.x * s2, sf1.y * s2};
    int nm1 = max(n - 1, 0);
    for (int b = 0; b < nmax; b += 16) {
        int2 e[16];
        #pragma unroll
        for (int j = 0; j < 16; ++j) {
            int cidx = min(o0 + min(b + j, nm1), N_EDGES - 1);
            e[j] = csr[cidx];                     // uniform per half-wave -> broadcast
        }
        uint2 u[16];
        #pragma unroll
        for (int j = 0; j < 16; ++j)
            u[j] = *(const uint2*)(X16 + (long)e[j].x * K1P + sl * 4);
        #pragma unroll
        for (int j = 0; j < 16; ++j) {
            float c = ((b + j) < n) ? __int_as_float(e[j].y) : 0.0f;
            float2 f0 = __half22float2(*(__half2*)&u[j].x);
            float2 f1 = __half22float2(*(__half2*)&u[j].y);
            acc.x += c * f0.x; acc.y += c * f0.y; acc.z += c * f1.x; acc.w += c * f1.y;
        }
    }
    __half2 h0 = __floats2half2_rn(acc.x, acc.y);
    __half2 h1 = __floats2half2_rn(acc.z, acc.w);
    uint2 o; o.x = *(unsigned*)&h0; o.y = *(unsigned*)&h1;
    *(uint2*)(aX + (long)v * K1P + sl * 4) = o;
}

// ---------------- fused GEMM1+GEMM2: T2 = (relu(aX@W1t^T + b1)) @ W2t^T ----------------
// One 64-row block: phase1 -> H1 tile (64x352 fp16) in LDS -> phase2 -> T2 (width 192).
__global__ __launch_bounds__(256) void k_gemm_fused(
        const ushort_t* __restrict__ aX,    // [MPAD][128]
        const ushort_t* __restrict__ w1t,   // [384][128] rows 0..351 used
        const float* __restrict__ b1,       // [336]
        const ushort_t* __restrict__ w2t,   // [192][352]
        ushort_t* __restrict__ T2) {        // [MPAD][192]
    __shared__ ushort_t As[64][40];
    __shared__ ushort_t Bs[352][40];
    __shared__ ushort_t H1s[64][360];
    const int tid = threadIdx.x;
    const int row0 = blockIdx.x * 64;
    const int w = tid >> 6, l = tid & 63;
    const int wm = w >> 1, wn = w & 1;
    const int lm = l & 15, lq = l >> 4;

    // ---- phase 1: H1tile = relu(aX[row0:+64][0:128] @ w1t[0:352]^T + b1) ----
    f32x4 acc1[2][11];
    #pragma unroll
    for (int i = 0; i < 2; ++i)
        #pragma unroll
        for (int j = 0; j < 11; ++j) acc1[i][j] = (f32x4){0.f, 0.f, 0.f, 0.f};

    for (int k0 = 0; k0 < K1P; k0 += 32) {
        {   // stage As: 64 rows x 4 segs = 256
            int r = tid >> 2, s = (tid & 3) * 8;
            *(int4*)&As[r][s] = *(const int4*)&aX[(long)(row0 + r) * K1P + k0 + s];
        }
        #pragma unroll
        for (int it = 0; it < 6; ++it) {   // stage Bs: 352 rows x 4 segs = 1408
            int f = tid + it * 256;
            if (f < 1408) {
                int r = f >> 2, s = (f & 3) * 8;
                *(int4*)&Bs[r][s] = *(const int4*)&w1t[(long)r * K1P + k0 + s];
            }
        }
        __syncthreads();
        f16x8 af0 = *(const f16x8*)&As[wm * 32 + lm][lq * 8];
        f16x8 af1 = *(const f16x8*)&As[wm * 32 + 16 + lm][lq * 8];
        #pragma unroll
        for (int ns = 0; ns < 11; ++ns) {
            f16x8 bf = *(const f16x8*)&Bs[wn * 176 + ns * 16 + lm][lq * 8];
            acc1[0][ns] = __builtin_amdgcn_mfma_f32_16x16x32_f16(af0, bf, acc1[0][ns], 0, 0, 0);
            acc1[1][ns] = __builtin_amdgcn_mfma_f32_16x16x32_f16(af1, bf, acc1[1][ns], 0, 0, 0);
        }
        __syncthreads();
    }
    // write H1 tile to LDS with bias+relu (C/D layout: col=lm, row=lq*4+i)
    #pragma unroll
    for (int ms = 0; ms < 2; ++ms)
        #pragma unroll
        for (int ns = 0; ns < 11; ++ns) {
            int col = wn * 176 + ns * 16 + lm;
            float bb = (col < F1) ? b1[col] : 0.0f;
            #pragma unroll
            for (int i = 0; i < 4; ++i) {
                int r = wm * 32 + ms * 16 + lq * 4 + i;
                H1s[r][col] = f16_bits(fmaxf(acc1[ms][ns][i] + bb, 0.0f));
            }
        }
    __syncthreads();

    // ---- phase 2: T2tile = H1tile @ w2t^T ----
    f32x4 acc2[2][6];
    #pragma unroll
    for (int i = 0; i < 2; ++i)
        #pragma unroll
        for (int j = 0; j < 6; ++j) acc2[i][j] = (f32x4){0.f, 0.f, 0.f, 0.f};

    for (int k0 = 0; k0 < K2P; k0 += 32) {
        #pragma unroll
        for (int it = 0; it < 3; ++it) {   // stage Bs2: 192 rows x 4 segs = 768
            int f = tid + it * 256;
            int r = f >> 2, s = (f & 3) * 8;
            *(int4*)&Bs[r][s] = *(const int4*)&w2t[(long)r * K2P + k0 + s];
        }
        __syncthreads();
        f16x8 af0 = *(const f16x8*)&H1s[wm * 32 + lm][k0 + lq * 8];
        f16x8 af1 = *(const f16x8*)&H1s[wm * 32 + 16 + lm][k0 + lq * 8];
        #pragma unroll
        for (int ns = 0; ns < 6; ++ns) {
            f16x8 bf = *(const f16x8*)&Bs[wn * 96 + ns * 16 + lm][lq * 8];
            acc2[0][ns] = __builtin_amdgcn_mfma_f32_16x16x32_f16(af0, bf, acc2[0][ns], 0, 0, 0);
            acc2[1][ns] = __builtin_amdgcn_mfma_f32_16x16x32_f16(af1, bf, acc2[1][ns], 0, 0, 0);
        }
        __syncthreads();
    }
    #pragma unroll
    for (int ms = 0; ms < 2; ++ms)
        #pragma unroll
        for (int ns = 0; ns < 6; ++ns) {
            int col = wn * 96 + ns * 16 + lm;
            #pragma unroll
            for (int i = 0; i < 4; ++i) {
                int r = row0 + wm * 32 + ms * 16 + lq * 4 + i;
                T2[(long)r * T2W + col] = f16_bits(acc2[ms][ns][i]);
            }
        }
}

// ---------------- agg layer 2: 2 nodes/wave, depth-16, + bias + relu -> fp16 ----------------
__global__ __launch_bounds__(256) void k_agg2(const ushort_t* __restrict__ T16,   // [MPAD][192]
                                              const int* __restrict__ off,
                                              const int2* __restrict__ csr,
                                              const float* __restrict__ dinv,
                                              const float* __restrict__ b2,
                                              ushort_t* __restrict__ out2) {      // [N][168]
    int w = (blockIdx.x * 256 + threadIdx.x) >> 6;
    int lane = threadIdx.x & 63;
    if (w >= N_NODES / 2) return;
    const int g = lane >> 5, sl = lane & 31;
    const int v = 2 * w + g;
    const bool act = sl < 21;                     // 21 lanes x 8 halves = 168
    int o0A = off[2 * w], oM = off[2 * w + 1], o1B = off[2 * w + 2];
    int o0 = g ? oM : o0A;
    int n  = g ? (o1B - oM) : (oM - o0A);
    int nmax = max(oM - o0A, o1B - oM);
    float di = dinv[v];
    float4 a0 = {0, 0, 0, 0}, a1 = {0, 0, 0, 0};
    if (act) {
        uint4 u = *(const uint4*)(T16 + (long)v * T2W + sl * 8);
        float2 f0 = __half22float2(*(__half2*)&u.x);
        float2 f1 = __half22float2(*(__half2*)&u.y);
        float2 f2 = __half22float2(*(__half2*)&u.z);
        float2 f3 = __half22float2(*(__half2*)&u.w);
        float s2 = di * di;
        a0.x = f0.x * s2; a0.y = f0.y * s2; a0.z = f1.x * s2; a0.w = f1.y * s2;
        a1.x = f2.x * s2; a1.y = f2.y * s2; a1.z = f3.x * s2; a1.w = f3.y * s2;
    }
    int nm1 = max(n - 1, 0);
    for (int b = 0; b < nmax; b += 16) {
        int2 e[16];
        #pragma unroll
        for (int j = 0; j < 16; ++j) {
            int cidx = min(o0 + min(b + j, nm1), N_EDGES - 1);
            e[j] = csr[cidx];
        }
        uint4 u[16];
        #pragma unroll
        for (int j = 0; j < 16; ++j) {
            int s = ((b + j) < n) ? e[j].x : v;
            if (act) u[j] = *(const uint4*)(T16 + (long)s * T2W + sl * 8);
        }
        #pragma unroll
        for (int j = 0; j < 16; ++j) {
            float c = ((b + j) < n) ? __int_as_float(e[j].y) : 0.0f;
            float2 f0 = __half22float2(*(__half2*)&u[j].x);
            float2 f1 = __half22float2(*(__half2*)&u[j].y);
            float2 f2 = __half22float2(*(__half2*)&u[j].z);
            float2 f3 = __half22float2(*(__half2*)&u[j].w);
            a0.x += c * f0.x; a0.y += c * f0.y; a0.z += c * f1.x; a0.w += c * f1.y;
            a1.x += c * f2.x; a1.y += c * f2.y; a1.z += c * f3.x; a1.w += c * f3.y;
        }
    }
    if (act) {
        float4 bb0 = ((const float4*)b2)[sl * 2];
        float4 bb1 = ((const float4*)b2)[sl * 2 + 1];
        __half2 h0 = __floats2half2_rn(fmaxf(a0.x + bb0.x, 0.0f), fmaxf(a0.y + bb0.y, 0.0f));
        __half2 h1 = __floats2half2_rn(fmaxf(a0.z + bb0.z, 0.0f), fmaxf(a0.w + bb0.w, 0.0f));
        __half2 h2 = __floats2half2_rn(fmaxf(a1.x + bb1.x, 0.0f), fmaxf(a1.y + bb1.y, 0.0f));
        __half2 h3 = __floats2half2_rn(fmaxf(a1.z + bb1.z, 0.0f), fmaxf(a1.w + bb1.w, 0.0f));
        uint4 o;
        o.x = *(unsigned*)&h0; o.y = *(unsigned*)&h1;
        o.z = *(unsigned*)&h2; o.w = *(unsigned*)&h3;
        *(uint4*)(out2 + (long)v * F2 + sl * 8) = o;
    }
}

// ---------------- fused per-graph max pool + MLP head ----------------
__global__ __launch_bounds__(256) void k_pool_head(const ushort_t* __restrict__ out2,
        const int* __restrict__ r0, const int* __restrict__ r1,
        const float* __restrict__ Wg, const float* __restrict__ bg,
        const float* __restrict__ Wf, const float* __restrict__ bf,
        const float* __restrict__ Wo, const float* __restrict__ bo,
        float* __restrict__ out) {
    __shared__ float4 sm[4][F2 / 4];
    __shared__ float s0[F2];
    __shared__ float s1[84];
    __shared__ float s2[42];
    int gi = blockIdx.x;
    int slot = threadIdx.x >> 6, lane = threadIdx.x & 63;
    int a = r0[gi], b = r1[gi];
    if (lane < F2 / 4) {
        float4 mx = {0, 0, 0, 0};
        for (int v = a + slot; v < b; v += 4) {
            uint2 u = ((const uint2*)(out2 + (long)v * F2))[lane];
            float2 f0 = __half22float2(*(__half2*)&u.x);
            float2 f1 = __half22float2(*(__half2*)&u.y);
            mx.x = fmaxf(mx.x, f0.x); mx.y = fmaxf(mx.y, f0.y);
            mx.z = fmaxf(mx.z, f1.x); mx.w = fmaxf(mx.w, f1.y);
        }
        sm[slot][lane] = mx;
    }
    __syncthreads();
    if (slot == 0 && lane < F2 / 4) {
        float4 m0 = sm[0][lane], m1 = sm[1][lane], m2 = sm[2][lane], m3 = sm[3][lane];
        float4 r;
        r.x = fmaxf(fmaxf(m0.x, m1.x), fmaxf(m2.x, m3.x));
        r.y = fmaxf(fmaxf(m0.y, m1.y), fmaxf(m2.y, m3.y));
        r.z = fmaxf(fmaxf(m0.z, m1.z), fmaxf(m2.z, m3.z));
        r.w = fmaxf(fmaxf(m0.w, m1.w), fmaxf(m2.w, m3.w));
        ((float4*)s0)[lane] = r;
    }
    __syncthreads();
    int t = threadIdx.x;
    if (t < 84) {
        float acc = bg[t];
        #pragma unroll 4
        for (int k = 0; k < F2; ++k) acc += s0[k] * Wg[k * 84 + t];
        s1[t] = fmaxf(acc, 0.0f);
    }
    __syncthreads();
    if (t < 42) {
        float acc = bf[t];
        #pragma unroll 4
        for (int k = 0; k < 84; ++k) acc += s1[k] * Wf[k * 42 + t];
        s2[t] = fmaxf(acc, 0.0f);
    }
    __syncthreads();
    if (t == 0) {
        float acc = bo[0];
        for (int k = 0; k < 42; ++k) acc += s2[k] * Wo[k];
        out[gi] = acc;
    }
}

extern "C" void kernel_launch(void* const* d_in, const int* in_sizes, int n_in,
                              void* d_out, int out_size, void* d_ws, size_t ws_size,
                              hipStream_t stream) {
    const float* x   = (const float*)d_in[0];
    const int*   ei  = (const int*)d_in[1];
    const int*   bat = (const int*)d_in[2];
    const float* W1  = (const float*)d_in[3];
    const float* b1  = (const float*)d_in[4];
    const float* W2  = (const float*)d_in[5];
    const float* b2  = (const float*)d_in[6];
    const float* Wg  = (const float*)d_in[7];
    const float* bg  = (const float*)d_in[8];
    const float* Wf  = (const float*)d_in[9];
    const float* bf  = (const float*)d_in[10];
    const float* Wo  = (const float*)d_in[11];
    const float* bo  = (const float*)d_in[12];
    float* out = (float*)d_out;

    // ---- workspace carve-up (16B-aligned chunks; dcount+cur adjacent) ----
    char* p = (char*)d_ws;
    float* dinv     = (float*)p; p += 50048 * 4;
    int*   dcount   = (int*)p;   p += 50048 * 4;
    int*   cur      = (int*)p;   p += 50048 * 4;
    int*   off      = (int*)p;   p += 50064 * 4;
    int*   partials = (int*)p;   p += 64 * 4;
    int*   rng0     = (int*)p;   p += 256 * 4;
    int*   rng1     = (int*)p;   p += 256 * 4;
    int2*  csr      = (int2*)p;  p += (long)N_EDGES * 8;
    ushort_t* x16   = (ushort_t*)p; p += (long)N_NODES * K1P * 2;   // padded 128
    ushort_t* aX    = (ushort_t*)p; p += (long)MPAD * K1P * 2;
    ushort_t* w1t   = (ushort_t*)p; p += (long)384 * K1P * 2;
    ushort_t* w2t   = (ushort_t*)p; p += (long)192 * K2P * 2;
    ushort_t* t16   = (ushort_t*)p; p += (long)MPAD * T2W * 2;      // padded 192
    ushort_t* o16   = (ushort_t*)p; p += (long)N_NODES * F2 * 2;

    const int* src = ei;
    const int* dst = ei + N_EDGES;
    const int B = 256;

    // ---- preproc ----
    k_zero_int<<<(2 * 50048 + B - 1) / B, B, 0, stream>>>(dcount, 2 * 50048);
    k_prep<<<PREP_BLOCKS, B, 0, stream>>>(x, dst, W1, W2, bat, x16, dcount, w1t, w2t, rng0, rng1);
    k_scan1<<<SCAN_BLOCKS, SCAN_CHUNK, 0, stream>>>(dcount, off, partials, dinv, N_NODES);
    k_scan3<<<SCAN_BLOCKS, SCAN_CHUNK, 0, stream>>>(off, partials, N_NODES);
    k_scatter<<<(N_EDGES / 2 + B - 1) / B, B, 0, stream>>>(src, dst, off, cur, dinv, csr, N_EDGES / 2);

    // ---- layer 1 agg + fused GEMM1/GEMM2 ----
    k_agg1<<<(N_NODES / 2 * 64) / 256, 256, 0, stream>>>(x16, off, csr, dinv, aX);
    k_gemm_fused<<<MPAD / 64, 256, 0, stream>>>(aX, w1t, b1, w2t, t16);

    // ---- layer 2 agg ----
    k_agg2<<<(N_NODES / 2 * 64) / 256, 256, 0, stream>>>(t16, off, csr, dinv, b2, o16);

    // ---- pool + head fused ----
    k_pool_head<<<NGRAPH, 256, 0, stream>>>(o16, rng0, rng1, Wg, bg, Wf, bf, Wo, bo, out);
}

// Round 11
// 280.403 us; speedup vs baseline: 1.5350x; 1.0145x over previous
//
#include <hip/hip_runtime.h>
#include <hip/hip_fp16.h>

#define N_NODES 50000
#define MPAD    50048            // 782 * 64
#define N_EDGES 500000
#define F_IN    112
#define K1P     128              // F_IN padded (halves per x16/aX row)
#define F1      336
#define K2P     352              // F1 padded to 32-multiple
#define F2      168
#define NGRAPH  256
#define SCAN_CHUNK 1024
#define SCAN_BLOCKS ((N_NODES + SCAN_CHUNK - 1) / SCAN_CHUNK)   // 49

typedef __attribute__((ext_vector_type(8))) _Float16 f16x8;
typedef __attribute__((ext_vector_type(4))) float f32x4;
typedef unsigned short ushort_t;

__device__ __forceinline__ ushort_t f16_bits(float x) {
    __half h = __float2half_rn(x);
    return *(ushort_t*)&h;
}

// ---------------- small utility kernels ----------------
__global__ void k_zero_int(int* p, int n) {
    int i = blockIdx.x * blockDim.x + threadIdx.x;
    if (i < n) p[i] = 0;
}

// ---------------- fused prep: cvtX(pad128) | count_deg | cvtW1 | cvtW2 | ranges ----------------
#define CVX_BLOCKS  ((N_NODES * 32) / 256)                 // 6250 (uint2 per thread)
#define CNT_BLOCKS  ((N_EDGES / 2 + 255) / 256)            // 977
#define CVW1_BLOCKS ((384 * K1P + 255) / 256)              // 192
#define CVW2_BLOCKS ((192 * K2P + 255) / 256)              // 264
#define RNG_BLOCKS  ((N_NODES + 255) / 256)                // 196
#define PREP_BLOCKS (CVX_BLOCKS + CNT_BLOCKS + CVW1_BLOCKS + CVW2_BLOCKS + RNG_BLOCKS)

__global__ __launch_bounds__(256) void k_prep(const float* __restrict__ x,
                                              const int* __restrict__ dst,
                                              const float* __restrict__ W1,
                                              const float* __restrict__ W2,
                                              const int* __restrict__ batch,
                                              ushort_t* __restrict__ x16,   // [N][128]
                                              int* __restrict__ dcount,
                                              ushort_t* __restrict__ w1t,   // [384][128]
                                              ushort_t* __restrict__ w2t,   // [192][352]
                                              int* __restrict__ r0, int* __restrict__ r1) {
    int bid = blockIdx.x;
    int t = threadIdx.x;
    if (bid < CVX_BLOCKS) {                       // X fp32 -> fp16, padded rows of 128 halves
        int i = bid * 256 + t;                    // uint2 (4 halves) index; i = v*32 + c
        int v = i >> 5, c = i & 31;
        uint2 u = {0, 0};
        if (c < 28) {
            float4 f = *(const float4*)&x[(long)v * F_IN + c * 4];
            __half2 h0 = __floats2half2_rn(f.x, f.y);
            __half2 h1 = __floats2half2_rn(f.z, f.w);
            u.x = *(unsigned*)&h0; u.y = *(unsigned*)&h1;
        }
        ((uint2*)x16)[i] = u;
        return;
    }
    bid -= CVX_BLOCKS;
    if (bid < CNT_BLOCKS) {                       // degree count, 2 edges/thread
        int i = bid * 256 + t;
        if (i < N_EDGES / 2) {
            int2 d = ((const int2*)dst)[i];
            atomicAdd(&dcount[d.x], 1);
            atomicAdd(&dcount[d.y], 1);
        }
        return;
    }
    bid -= CNT_BLOCKS;
    if (bid < CVW1_BLOCKS) {                      // W1[K,N] -> w1t[n][k]
        int idx = bid * 256 + t;
        if (idx < 384 * K1P) {
            int n = idx / K1P, k = idx % K1P;
            float v = (n < F1 && k < F_IN) ? W1[k * F1 + n] : 0.0f;
            w1t[idx] = f16_bits(v);
        }
        return;
    }
    bid -= CVW1_BLOCKS;
    if (bid < CVW2_BLOCKS) {                      // W2[K,N] -> w2t[n][k]
        int idx = bid * 256 + t;
        if (idx < 192 * K2P) {
            int n = idx / K2P, k = idx % K2P;
            float v = (n < F2 && k < F1) ? W2[k * F2 + n] : 0.0f;
            w2t[idx] = f16_bits(v);
        }
        return;
    }
    bid -= CVW2_BLOCKS;
    {                                             // per-graph ranges (batch sorted)
        int v = bid * 256 + t;
        if (v >= N_NODES) return;
        int b = batch[v];
        if (v == 0 || batch[v - 1] != b) r0[b] = v;
        if (v == N_NODES - 1 || batch[v + 1] != b) r1[b] = v + 1;
    }
}

// ---------------- scan pass 1 (dinv fused) ----------------
__global__ __launch_bounds__(SCAN_CHUNK) void k_scan1(const int* __restrict__ dcount,
                                                      int* __restrict__ off,
                                                      int* __restrict__ partials,
                                                      float* __restrict__ dinv, int n) {
    __shared__ int s[SCAN_CHUNK];
    int t = threadIdx.x;
    int i = blockIdx.x * SCAN_CHUNK + t;
    int val = (i < n) ? dcount[i] : 0;
    s[t] = val;
    __syncthreads();
    for (int d = 1; d < SCAN_CHUNK; d <<= 1) {
        int x = (t >= d) ? s[t - d] : 0;
        __syncthreads();
        s[t] += x;
        __syncthreads();
    }
    if (i < n) {
        off[i] = s[t] - val;
        dinv[i] = rsqrtf((float)val + 1.0f);      // +1 self-loop
    }
    if (t == SCAN_CHUNK - 1) partials[blockIdx.x] = s[t];
}
// scan pass 2+3 merged
__global__ __launch_bounds__(SCAN_CHUNK) void k_scan3(int* __restrict__ off,
                                                      const int* __restrict__ partials, int n) {
    __shared__ int tmp[SCAN_BLOCKS];
    __shared__ int pref[SCAN_BLOCKS];
    int t = threadIdx.x;
    if (t < SCAN_BLOCKS) tmp[t] = partials[t];
    __syncthreads();
    if (t == 0) {
        int run = 0;
        for (int j = 0; j < SCAN_BLOCKS; ++j) { pref[j] = run; run += tmp[j]; }
    }
    __syncthreads();
    int i = blockIdx.x * SCAN_CHUNK + t;
    if (i < n) off[i] += pref[blockIdx.x];
    if (i == n) off[i] = N_EDGES;
}

// ---------------- scatter edges into dst-sorted CSR, 2 edges/thread ----------------
__global__ void k_scatter(const int* __restrict__ src, const int* __restrict__ dst,
                          const int* __restrict__ off, int* __restrict__ cur,
                          const float* __restrict__ dinv,
                          int2* __restrict__ csr, int e2) {
    int i = blockIdx.x * blockDim.x + threadIdx.x;
    if (i >= e2) return;
    int2 s2 = ((const int2*)src)[i];
    int2 d2 = ((const int2*)dst)[i];
    {
        int pos = atomicAdd(&cur[d2.x], 1);
        int2 rec; rec.x = s2.x; rec.y = __float_as_int(dinv[s2.x] * dinv[d2.x]);
        csr[off[d2.x] + pos] = rec;
    }
    {
        int pos = atomicAdd(&cur[d2.y], 1);
        int2 rec; rec.x = s2.y; rec.y = __float_as_int(dinv[s2.y] * dinv[d2.y]);
        csr[off[d2.y] + pos] = rec;
    }
}

// ---------------- agg layer 1: 2 nodes/wave, depth-8, padded 256B rows ----------------
__global__ __launch_bounds__(256) void k_agg1(const ushort_t* __restrict__ X16,
                                              const int* __restrict__ off,
                                              const int2* __restrict__ csr,
                                              const float* __restrict__ dinv,
                                              ushort_t* __restrict__ aX) {
    int w = (blockIdx.x * 256 + threadIdx.x) >> 6;
    int lane = threadIdx.x & 63;
    if (w >= N_NODES / 2) return;
    const int g = lane >> 5, sl = lane & 31;
    const int v = 2 * w + g;
    int o0A = off[2 * w], oM = off[2 * w + 1], o1B = off[2 * w + 2];
    int o0 = g ? oM : o0A;
    int n  = g ? (o1B - oM) : (oM - o0A);
    int nmax = max(oM - o0A, o1B - oM);
    float di = dinv[v];
    float s2 = di * di;
    // all 32 lanes live: pad cols are zero in X16
    uint2 us = *(const uint2*)(X16 + (long)v * K1P + sl * 4);
    float2 sf0 = __half22float2(*(__half2*)&us.x);
    float2 sf1 = __half22float2(*(__half2*)&us.y);
    float4 acc = {sf0.x * s2, sf0.y * s2, sf1.x * s2, sf1.y * s2};
    int nm1 = max(n - 1, 0);
    for (int b = 0; b < nmax; b += 8) {
        int2 e[8];
        #pragma unroll
        for (int j = 0; j < 8; ++j) {
            int cidx = min(o0 + min(b + j, nm1), N_EDGES - 1);
            e[j] = csr[cidx];                     // uniform per half-wave -> broadcast
        }
        uint2 u[8];
        #pragma unroll
        for (int j = 0; j < 8; ++j)
            u[j] = *(const uint2*)(X16 + (long)e[j].x * K1P + sl * 4);
        #pragma unroll
        for (int j = 0; j < 8; ++j) {
            float c = ((b + j) < n) ? __int_as_float(e[j].y) : 0.0f;
            float2 f0 = __half22float2(*(__half2*)&u[j].x);
            float2 f1 = __half22float2(*(__half2*)&u[j].y);
            acc.x += c * f0.x; acc.y += c * f0.y; acc.z += c * f1.x; acc.w += c * f1.y;
        }
    }
    __half2 h0 = __floats2half2_rn(acc.x, acc.y);
    __half2 h1 = __floats2half2_rn(acc.z, acc.w);
    uint2 o; o.x = *(unsigned*)&h0; o.y = *(unsigned*)&h1;
    *(uint2*)(aX + (long)v * K1P + sl * 4) = o;
}

// ---------------- fused GEMM1+GEMM2: T2 = (relu(aX@W1t^T + b1)) @ W2t^T ----------------
// One 64-row block: phase1 -> H1 tile (64x352 fp16) in LDS -> phase2 -> T2 (width 168, unpadded).
__global__ __launch_bounds__(256) void k_gemm_fused(
        const ushort_t* __restrict__ aX,    // [MPAD][128]
        const ushort_t* __restrict__ w1t,   // [384][128] rows 0..351 used
        const float* __restrict__ b1,       // [336]
        const ushort_t* __restrict__ w2t,   // [192][352]
        ushort_t* __restrict__ T2) {        // [MPAD][168]
    __shared__ ushort_t As[64][40];
    __shared__ ushort_t Bs[352][40];
    __shared__ ushort_t H1s[64][360];
    const int tid = threadIdx.x;
    const int row0 = blockIdx.x * 64;
    const int w = tid >> 6, l = tid & 63;
    const int wm = w >> 1, wn = w & 1;
    const int lm = l & 15, lq = l >> 4;

    // ---- phase 1 ----
    f32x4 acc1[2][11];
    #pragma unroll
    for (int i = 0; i < 2; ++i)
        #pragma unroll
        for (int j = 0; j < 11; ++j) acc1[i][j] = (f32x4){0.f, 0.f, 0.f, 0.f};

    for (int k0 = 0; k0 < K1P; k0 += 32) {
        {   // stage As
            int r = tid >> 2, s = (tid & 3) * 8;
            *(int4*)&As[r][s] = *(const int4*)&aX[(long)(row0 + r) * K1P + k0 + s];
        }
        #pragma unroll
        for (int it = 0; it < 6; ++it) {   // stage Bs: 352 rows x 4 segs = 1408
            int f = tid + it * 256;
            if (f < 1408) {
                int r = f >> 2, s = (f & 3) * 8;
                *(int4*)&Bs[r][s] = *(const int4*)&w1t[(long)r * K1P + k0 + s];
            }
        }
        __syncthreads();
        f16x8 af0 = *(const f16x8*)&As[wm * 32 + lm][lq * 8];
        f16x8 af1 = *(const f16x8*)&As[wm * 32 + 16 + lm][lq * 8];
        #pragma unroll
        for (int ns = 0; ns < 11; ++ns) {
            f16x8 bf = *(const f16x8*)&Bs[wn * 176 + ns * 16 + lm][lq * 8];
            acc1[0][ns] = __builtin_amdgcn_mfma_f32_16x16x32_f16(af0, bf, acc1[0][ns], 0, 0, 0);
            acc1[1][ns] = __builtin_amdgcn_mfma_f32_16x16x32_f16(af1, bf, acc1[1][ns], 0, 0, 0);
        }
        __syncthreads();
    }
    // write H1 tile to LDS with bias+relu (C/D layout: col=lm, row=lq*4+i)
    #pragma unroll
    for (int ms = 0; ms < 2; ++ms)
        #pragma unroll
        for (int ns = 0; ns < 11; ++ns) {
            int col = wn * 176 + ns * 16 + lm;
            float bb = (col < F1) ? b1[col] : 0.0f;
            #pragma unroll
            for (int i = 0; i < 4; ++i) {
                int r = wm * 32 + ms * 16 + lq * 4 + i;
                H1s[r][col] = f16_bits(fmaxf(acc1[ms][ns][i] + bb, 0.0f));
            }
        }
    __syncthreads();

    // ---- phase 2 ----
    f32x4 acc2[2][6];
    #pragma unroll
    for (int i = 0; i < 2; ++i)
        #pragma unroll
        for (int j = 0; j < 6; ++j) acc2[i][j] = (f32x4){0.f, 0.f, 0.f, 0.f};

    for (int k0 = 0; k0 < K2P; k0 += 32) {
        #pragma unroll
        for (int it = 0; it < 3; ++it) {   // stage Bs2: 192 rows x 4 segs = 768
            int f = tid + it * 256;
            int r = f >> 2, s = (f & 3) * 8;
            *(int4*)&Bs[r][s] = *(const int4*)&w2t[(long)r * K2P + k0 + s];
        }
        __syncthreads();
        f16x8 af0 = *(const f16x8*)&H1s[wm * 32 + lm][k0 + lq * 8];
        f16x8 af1 = *(const f16x8*)&H1s[wm * 32 + 16 + lm][k0 + lq * 8];
        #pragma unroll
        for (int ns = 0; ns < 6; ++ns) {
            f16x8 bf = *(const f16x8*)&Bs[wn * 96 + ns * 16 + lm][lq * 8];
            acc2[0][ns] = __builtin_amdgcn_mfma_f32_16x16x32_f16(af0, bf, acc2[0][ns], 0, 0, 0);
            acc2[1][ns] = __builtin_amdgcn_mfma_f32_16x16x32_f16(af1, bf, acc2[1][ns], 0, 0, 0);
        }
        __syncthreads();
    }
    #pragma unroll
    for (int ms = 0; ms < 2; ++ms)
        #pragma unroll
        for (int ns = 0; ns < 6; ++ns) {
            int col = wn * 96 + ns * 16 + lm;
            if (col < F2) {
                #pragma unroll
                for (int i = 0; i < 4; ++i) {
                    int r = row0 + wm * 32 + ms * 16 + lq * 4 + i;
                    T2[(long)r * F2 + col] = f16_bits(acc2[ms][ns][i]);
                }
            }
        }
}

// ---------------- agg layer 2: 2 nodes/wave, depth-8, + bias + relu -> fp16 ----------------
__global__ __launch_bounds__(256) void k_agg2(const ushort_t* __restrict__ T16,   // [MPAD][168]
                                              const int* __restrict__ off,
                                              const int2* __restrict__ csr,
                                              const float* __restrict__ dinv,
                                              const float* __restrict__ b2,
                                              ushort_t* __restrict__ out2) {      // [N][168]
    int w = (blockIdx.x * 256 + threadIdx.x) >> 6;
    int lane = threadIdx.x & 63;
    if (w >= N_NODES / 2) return;
    const int g = lane >> 5, sl = lane & 31;
    const int v = 2 * w + g;
    const bool act = sl < 21;                     // 21 lanes x 8 halves = 168
    int o0A = off[2 * w], oM = off[2 * w + 1], o1B = off[2 * w + 2];
    int o0 = g ? oM : o0A;
    int n  = g ? (o1B - oM) : (oM - o0A);
    int nmax = max(oM - o0A, o1B - oM);
    float di = dinv[v];
    float4 a0 = {0, 0, 0, 0}, a1 = {0, 0, 0, 0};
    if (act) {
        uint4 u = *(const uint4*)(T16 + (long)v * F2 + sl * 8);
        float2 f0 = __half22float2(*(__half2*)&u.x);
        float2 f1 = __half22float2(*(__half2*)&u.y);
        float2 f2 = __half22float2(*(__half2*)&u.z);
        float2 f3 = __half22float2(*(__half2*)&u.w);
        float s2 = di * di;
        a0.x = f0.x * s2; a0.y = f0.y * s2; a0.z = f1.x * s2; a0.w = f1.y * s2;
        a1.x = f2.x * s2; a1.y = f2.y * s2; a1.z = f3.x * s2; a1.w = f3.y * s2;
    }
    int nm1 = max(n - 1, 0);
    for (int b = 0; b < nmax; b += 8) {
        int2 e[8];
        #pragma unroll
        for (int j = 0; j < 8; ++j) {
            int cidx = min(o0 + min(b + j, nm1), N_EDGES - 1);
            e[j] = csr[cidx];
        }
        uint4 u[8];
        #pragma unroll
        for (int j = 0; j < 8; ++j) {
            int s = ((b + j) < n) ? e[j].x : v;
            if (act) u[j] = *(const uint4*)(T16 + (long)s * F2 + sl * 8);
        }
        #pragma unroll
        for (int j = 0; j < 8; ++j) {
            float c = ((b + j) < n) ? __int_as_float(e[j].y) : 0.0f;
            float2 f0 = __half22float2(*(__half2*)&u[j].x);
            float2 f1 = __half22float2(*(__half2*)&u[j].y);
            float2 f2 = __half22float2(*(__half2*)&u[j].z);
            float2 f3 = __half22float2(*(__half2*)&u[j].w);
            a0.x += c * f0.x; a0.y += c * f0.y; a0.z += c * f1.x; a0.w += c * f1.y;
            a1.x += c * f2.x; a1.y += c * f2.y; a1.z += c * f3.x; a1.w += c * f3.y;
        }
    }
    if (act) {
        float4 bb0 = ((const float4*)b2)[sl * 2];
        float4 bb1 = ((const float4*)b2)[sl * 2 + 1];
        __half2 h0 = __floats2half2_rn(fmaxf(a0.x + bb0.x, 0.0f), fmaxf(a0.y + bb0.y, 0.0f));
        __half2 h1 = __floats2half2_rn(fmaxf(a0.z + bb0.z, 0.0f), fmaxf(a0.w + bb0.w, 0.0f));
        __half2 h2 = __floats2half2_rn(fmaxf(a1.x + bb1.x, 0.0f), fmaxf(a1.y + bb1.y, 0.0f));
        __half2 h3 = __floats2half2_rn(fmaxf(a1.z + bb1.z, 0.0f), fmaxf(a1.w + bb1.w, 0.0f));
        uint4 o;
        o.x = *(unsigned*)&h0; o.y = *(unsigned*)&h1;
        o.z = *(unsigned*)&h2; o.w = *(unsigned*)&h3;
        *(uint4*)(out2 + (long)v * F2 + sl * 8) = o;
    }
}

// ---------------- fused per-graph max pool + MLP head ----------------
__global__ __launch_bounds__(256) void k_pool_head(const ushort_t* __restrict__ out2,
        const int* __restrict__ r0, const int* __restrict__ r1,
        const float* __restrict__ Wg, const float* __restrict__ bg,
        const float* __restrict__ Wf, const float* __restrict__ bf,
        const float* __restrict__ Wo, const float* __restrict__ bo,
        float* __restrict__ out) {
    __shared__ float4 sm[4][F2 / 4];
    __shared__ float s0[F2];
    __shared__ float s1[84];
    __shared__ float s2[42];
    int gi = blockIdx.x;
    int slot = threadIdx.x >> 6, lane = threadIdx.x & 63;
    int a = r0[gi], b = r1[gi];
    if (lane < F2 / 4) {
        float4 mx = {0, 0, 0, 0};
        for (int v = a + slot; v < b; v += 4) {
            uint2 u = ((const uint2*)(out2 + (long)v * F2))[lane];
            float2 f0 = __half22float2(*(__half2*)&u.x);
            float2 f1 = __half22float2(*(__half2*)&u.y);
            mx.x = fmaxf(mx.x, f0.x); mx.y = fmaxf(mx.y, f0.y);
            mx.z = fmaxf(mx.z, f1.x); mx.w = fmaxf(mx.w, f1.y);
        }
        sm[slot][lane] = mx;
    }
    __syncthreads();
    if (slot == 0 && lane < F2 / 4) {
        float4 m0 = sm[0][lane], m1 = sm[1][lane], m2 = sm[2][lane], m3 = sm[3][lane];
        float4 r;
        r.x = fmaxf(fmaxf(m0.x, m1.x), fmaxf(m2.x, m3.x));
        r.y = fmaxf(fmaxf(m0.y, m1.y), fmaxf(m2.y, m3.y));
        r.z = fmaxf(fmaxf(m0.z, m1.z), fmaxf(m2.z, m3.z));
        r.w = fmaxf(fmaxf(m0.w, m1.w), fmaxf(m2.w, m3.w));
        ((float4*)s0)[lane] = r;
    }
    __syncthreads();
    int t = threadIdx.x;
    if (t < 84) {
        float acc = bg[t];
        #pragma unroll 4
        for (int k = 0; k < F2; ++k) acc += s0[k] * Wg[k * 84 + t];
        s1[t] = fmaxf(acc, 0.0f);
    }
    __syncthreads();
    if (t < 42) {
        float acc = bf[t];
        #pragma unroll 4
        for (int k = 0; k < 84; ++k) acc += s1[k] * Wf[k * 42 + t];
        s2[t] = fmaxf(acc, 0.0f);
    }
    __syncthreads();
    if (t == 0) {
        float acc = bo[0];
        for (int k = 0; k < 42; ++k) acc += s2[k] * Wo[k];
        out[gi] = acc;
    }
}

extern "C" void kernel_launch(void* const* d_in, const int* in_sizes, int n_in,
                              void* d_out, int out_size, void* d_ws, size_t ws_size,
                              hipStream_t stream) {
    const float* x   = (const float*)d_in[0];
    const int*   ei  = (const int*)d_in[1];
    const int*   bat = (const int*)d_in[2];
    const float* W1  = (const float*)d_in[3];
    const float* b1  = (const float*)d_in[4];
    const float* W2  = (const float*)d_in[5];
    const float* b2  = (const float*)d_in[6];
    const float* Wg  = (const float*)d_in[7];
    const float* bg  = (const float*)d_in[8];
    const float* Wf  = (const float*)d_in[9];
    const float* bf  = (const float*)d_in[10];
    const float* Wo  = (const float*)d_in[11];
    const float* bo  = (const float*)d_in[12];
    float* out = (float*)d_out;

    // ---- workspace carve-up (16B-aligned chunks; dcount+cur adjacent) ----
    char* p = (char*)d_ws;
    float* dinv     = (float*)p; p += 50048 * 4;
    int*   dcount   = (int*)p;   p += 50048 * 4;
    int*   cur      = (int*)p;   p += 50048 * 4;
    int*   off      = (int*)p;   p += 50064 * 4;
    int*   partials = (int*)p;   p += 64 * 4;
    int*   rng0     = (int*)p;   p += 256 * 4;
    int*   rng1     = (int*)p;   p += 256 * 4;
    int2*  csr      = (int2*)p;  p += (long)N_EDGES * 8;
    ushort_t* x16   = (ushort_t*)p; p += (long)N_NODES * K1P * 2;   // padded 128
    ushort_t* aX    = (ushort_t*)p; p += (long)MPAD * K1P * 2;
    ushort_t* w1t   = (ushort_t*)p; p += (long)384 * K1P * 2;
    ushort_t* w2t   = (ushort_t*)p; p += (long)192 * K2P * 2;
    ushort_t* t16   = (ushort_t*)p; p += (long)MPAD * F2 * 2;       // unpadded 168
    ushort_t* o16   = (ushort_t*)p; p += (long)N_NODES * F2 * 2;

    const int* src = ei;
    const int* dst = ei + N_EDGES;
    const int B = 256;

    // ---- preproc ----
    k_zero_int<<<(2 * 50048 + B - 1) / B, B, 0, stream>>>(dcount, 2 * 50048);
    k_prep<<<PREP_BLOCKS, B, 0, stream>>>(x, dst, W1, W2, bat, x16, dcount, w1t, w2t, rng0, rng1);
    k_scan1<<<SCAN_BLOCKS, SCAN_CHUNK, 0, stream>>>(dcount, off, partials, dinv, N_NODES);
    k_scan3<<<SCAN_BLOCKS, SCAN_CHUNK, 0, stream>>>(off, partials, N_NODES);
    k_scatter<<<(N_EDGES / 2 + B - 1) / B, B, 0, stream>>>(src, dst, off, cur, dinv, csr, N_EDGES / 2);

    // ---- layer 1 agg + fused GEMM1/GEMM2 ----
    k_agg1<<<(N_NODES / 2 * 64) / 256, 256, 0, stream>>>(x16, off, csr, dinv, aX);
    k_gemm_fused<<<MPAD / 64, 256, 0, stream>>>(aX, w1t, b1, w2t, t16);

    // ---- layer 2 agg ----
    k_agg2<<<(N_NODES / 2 * 64) / 256, 256, 0, stream>>>(t16, off, csr, dinv, b2, o16);

    // ---- pool + head fused ----
    k_pool_head<<<NGRAPH, 256, 0, stream>>>(o16, rng0, rng1, Wg, bg, Wf, bf, Wo, bo, out);
}